// Round 2
// baseline (14340.245 us; speedup 1.0000x reference)
//
#include <hip/hip_runtime.h>

// ---------------------------------------------------------------------------
// FEMBA full forward, f32. Shapes (fixed): B=32, L=2048, D=256, di=256, ds=8,
// dtr=16, K=4, nb=2, dirs=2, nc=10.
// Workspace: adaptive. Fixed ~130.4 MB (two 64MB hidden buffers + small) plus
// per-chunk scratch 6.55 MB per sequence in flight; batch is processed in
// chunks of CB sequences where CB is the largest of {32,16,8,4,2,1} fitting
// ws_size (runtime-constant => identical work every call, graph-safe).
// ---------------------------------------------------------------------------

__device__ __forceinline__ float fq_val(float x, float s){
  float q = rintf(x / s);                 // round-half-even == jnp.round
  q = fminf(fmaxf(q, -128.0f), 127.0f);   // clip(-QMAX-1, QMAX)
  return q * s;
}

// ---- generic absmax (grid) -> atomicMax on float bits --------------------
__global__ __launch_bounds__(256) void absmax_kernel(const float* __restrict__ x,
                                                     long long n, float* __restrict__ slot){
  float m = 0.0f;
  for (long long i = (long long)blockIdx.x * 256 + threadIdx.x; i < n;
       i += (long long)gridDim.x * 256)
    m = fmaxf(m, fabsf(x[i]));
  __shared__ float red[256];
  red[threadIdx.x] = m; __syncthreads();
  for (int s2 = 128; s2 > 0; s2 >>= 1){
    if (threadIdx.x < s2) red[threadIdx.x] = fmaxf(red[threadIdx.x], red[threadIdx.x + s2]);
    __syncthreads();
  }
  if (threadIdx.x == 0) atomicMax((unsigned int*)slot, __float_as_uint(red[0]));
}

// ---- quantize (n must be multiple of 256) --------------------------------
__global__ __launch_bounds__(256) void quant_kernel(const float* __restrict__ src,
                                                    float* __restrict__ dst,
                                                    const float* __restrict__ slot){
  long long i = (long long)blockIdx.x * 256 + threadIdx.x;
  float s = fmaxf(slot[0], 1e-8f) / 127.0f;
  dst[i] = fq_val(src[i], s);
}

// ---- single-block fq for small tensors -----------------------------------
__global__ __launch_bounds__(256) void fq_small(const float* __restrict__ src,
                                                float* __restrict__ dst, int n){
  __shared__ float red[256];
  __shared__ float sS;
  float m = 0.0f;
  for (int i = threadIdx.x; i < n; i += 256) m = fmaxf(m, fabsf(src[i]));
  red[threadIdx.x] = m; __syncthreads();
  for (int s2 = 128; s2 > 0; s2 >>= 1){
    if (threadIdx.x < s2) red[threadIdx.x] = fmaxf(red[threadIdx.x], red[threadIdx.x + s2]);
    __syncthreads();
  }
  if (threadIdx.x == 0) sS = fmaxf(red[0], 1e-8f) / 127.0f;
  __syncthreads();
  float s = sS;
  for (int i = threadIdx.x; i < n; i += 256) dst[i] = fq_val(src[i], s);
}

// ---- patchify with inline fq(x): h[b,w,g*32+c] = conv2x2(fq(x)) + patch_b -
__global__ __launch_bounds__(256) void patchify_kernel(const float* __restrict__ x,
                                                       const float* __restrict__ pwq,
                                                       const float* __restrict__ pb,
                                                       float* __restrict__ h,
                                                       const float* __restrict__ slot){
  long long idx = (long long)blockIdx.x * 256 + threadIdx.x;  // 16,777,216
  int d = (int)(idx & 255);
  int l = (int)((idx >> 8) & 2047);
  int b = (int)(idx >> 19);
  int c = d & 31, g = d >> 5;
  float s = fmaxf(slot[0], 1e-8f) / 127.0f;
  const float* xp = x + ((long long)(b * 16 + 2 * g) * 4096 + 2 * l);
  float acc = pb[c];
  acc += fq_val(xp[0],    s) * pwq[c * 4 + 0];
  acc += fq_val(xp[1],    s) * pwq[c * 4 + 1];
  acc += fq_val(xp[4096], s) * pwq[c * 4 + 2];
  acc += fq_val(xp[4097], s) * pwq[c * 4 + 3];
  h[idx] = acc;
}

// ---- h += pos (broadcast over batch) -------------------------------------
__global__ __launch_bounds__(256) void addpos_kernel(float* __restrict__ h,
                                                     const float* __restrict__ pos){
  long long i = (long long)blockIdx.x * 256 + threadIdx.x;
  h[i] += pos[i & 524287];
}

// ---- tiled fp32 GEMM: C(R,N) = A(R,K)@B(K,N); optional row-flip (within a
//      2048-row sequence) on A read or C write, optional accumulate on C ----
__global__ __launch_bounds__(256) void gemm64(const float* __restrict__ A,
                                              const float* __restrict__ Bw,
                                              float* __restrict__ C,
                                              int N, int K,
                                              int flipA, int flipC, int accum){
  __shared__ float As[32][68];  // [k][m], padded row
  __shared__ float Bs[32][64];  // [k][n]
  int tid = threadIdx.x;
  int bn = blockIdx.x, bm = blockIdx.y;
  int tx = tid & 15, ty = tid >> 4;

  int f0 = tid, f1 = tid + 256;
  int ar0 = f0 >> 3, ac0 = (f0 & 7) * 4;
  int ar1 = f1 >> 3, ac1 = (f1 & 7) * 4;
  int am0 = bm * 64 + ar0, am1 = bm * 64 + ar1;
  long long amr0 = flipA ? (((long long)(am0 >> 11)) << 11) + (2047 - (am0 & 2047)) : am0;
  long long amr1 = flipA ? (((long long)(am1 >> 11)) << 11) + (2047 - (am1 & 2047)) : am1;
  const float* Ap0 = A + amr0 * (long long)K + ac0;
  const float* Ap1 = A + amr1 * (long long)K + ac1;
  int br0 = f0 >> 4, bc0 = (f0 & 15) * 4;
  int br1 = f1 >> 4, bc1 = (f1 & 15) * 4;
  const float* Bp0 = Bw + (long long)br0 * N + bn * 64 + bc0;
  const float* Bp1 = Bw + (long long)br1 * N + bn * 64 + bc1;

  float acc[4][4] = {};
  for (int k0 = 0; k0 < K; k0 += 32){
    float4 a0v = *(const float4*)(Ap0 + k0);
    float4 a1v = *(const float4*)(Ap1 + k0);
    float4 b0v = *(const float4*)(Bp0 + (long long)k0 * N);
    float4 b1v = *(const float4*)(Bp1 + (long long)k0 * N);
    As[ac0 + 0][ar0] = a0v.x; As[ac0 + 1][ar0] = a0v.y;
    As[ac0 + 2][ar0] = a0v.z; As[ac0 + 3][ar0] = a0v.w;
    As[ac1 + 0][ar1] = a1v.x; As[ac1 + 1][ar1] = a1v.y;
    As[ac1 + 2][ar1] = a1v.z; As[ac1 + 3][ar1] = a1v.w;
    *(float4*)&Bs[br0][bc0] = b0v;
    *(float4*)&Bs[br1][bc1] = b1v;
    __syncthreads();
#pragma unroll
    for (int kk = 0; kk < 32; kk++){
      float4 av = *(const float4*)&As[kk][ty * 4];
      float4 bv = *(const float4*)&Bs[kk][tx * 4];
      float ar[4] = {av.x, av.y, av.z, av.w};
      float br[4] = {bv.x, bv.y, bv.z, bv.w};
#pragma unroll
      for (int i = 0; i < 4; i++)
#pragma unroll
        for (int j = 0; j < 4; j++)
          acc[i][j] = fmaf(ar[i], br[j], acc[i][j]);
    }
    __syncthreads();
  }
#pragma unroll
  for (int i = 0; i < 4; i++){
    int m = bm * 64 + ty * 4 + i;
    long long mr = flipC ? (((long long)(m >> 11)) << 11) + (2047 - (m & 2047)) : m;
    float* Cp = C + mr * (long long)N + bn * 64 + tx * 4;
    if (accum){
      Cp[0] += acc[i][0]; Cp[1] += acc[i][1]; Cp[2] += acc[i][2]; Cp[3] += acc[i][3];
    } else {
      float4 v = make_float4(acc[i][0], acc[i][1], acc[i][2], acc[i][3]);
      *(float4*)Cp = v;
    }
  }
}

// ---- depthwise causal conv (K=4) + SiLU; input = xz cols [0,256) ----------
__global__ __launch_bounds__(256) void conv_silu_kernel(const float* __restrict__ xz,
                                                        const float* __restrict__ cw,
                                                        const float* __restrict__ cb,
                                                        float* __restrict__ xs){
  long long idx = (long long)blockIdx.x * 256 + threadIdx.x;
  int d = (int)(idx & 255);
  long long bl = idx >> 8;
  int l = (int)(bl & 2047);
  const float* base = xz + (bl << 9) + d;   // row stride 512
  float w0 = cw[d*4], w1 = cw[d*4+1], w2 = cw[d*4+2], w3 = cw[d*4+3];
  float acc = cb[d] + w3 * base[0];
  if (l >= 1) acc += w2 * base[-512];
  if (l >= 2) acc += w1 * base[-1024];
  if (l >= 3) acc += w0 * base[-1536];
  xs[idx] = acc / (1.0f + expf(-acc));      // silu
}

// ---- proj = xs @ W_xp (K=256, N=32); 8 rows per block ---------------------
__global__ __launch_bounds__(256) void gemm_proj(const float* __restrict__ xs,
                                                 const float* __restrict__ W,
                                                 float* __restrict__ proj){
  __shared__ float As[2048];
  long long row0 = (long long)blockIdx.x * 8;
  for (int i = threadIdx.x; i < 2048; i += 256) As[i] = xs[row0 * 256 + i];
  __syncthreads();
  int r = threadIdx.x >> 5, cidx = threadIdx.x & 31;
  float acc = 0.0f;
#pragma unroll 8
  for (int k = 0; k < 256; k++) acc = fmaf(As[r * 256 + k], W[k * 32 + cidx], acc);
  proj[(row0 + r) * 32 + cidx] = acc;
}

// ---- dt = softplus(proj[:, :16] @ W_dt + b_dt) -> xz cols [0,256) ---------
__global__ __launch_bounds__(256) void dt_kernel(const float* __restrict__ proj,
                                                 const float* __restrict__ Wdt,
                                                 const float* __restrict__ bdt,
                                                 float* __restrict__ dtbuf){
  __shared__ float pr[16];
  long long row = blockIdx.x;
  if (threadIdx.x < 16) pr[threadIdx.x] = proj[row * 32 + threadIdx.x];
  __syncthreads();
  int d = threadIdx.x;
  float acc = bdt[d];
#pragma unroll
  for (int r = 0; r < 16; r++) acc = fmaf(pr[r], Wdt[r * 256 + d], acc);
  float sp = (acc > 0.0f) ? acc + log1pf(expf(-acc)) : log1pf(expf(acc));
  dtbuf[row * 512 + d] = sp;
}

// ---- selective scan over one chunk of CB sequences ------------------------
__global__ __launch_bounds__(256) void scan_kernel(const float* __restrict__ xzb,
                                                   float* __restrict__ xs,
                                                   const float* __restrict__ proj,
                                                   const float* __restrict__ A_log,
                                                   const float* __restrict__ Dsk){
  int t = blockIdx.x * 256 + threadIdx.x;     // CB*2048 threads
  int s = t & 7;
  int d = (t >> 3) & 255;
  int b = t >> 11;                            // chunk-local sequence
  float A  = -expf(A_log[d * 8 + s]);
  float Dv = Dsk[d];
  const float* dtp = xzb + ((long long)b * 2048) * 512 + d;
  const float* zp  = dtp + 256;
  float* xsp = xs + ((long long)b * 2048) * 256 + d;
  const float* pp = proj + ((long long)b * 2048) * 32;
  float h = 0.0f;
  float dt = dtp[0], x = xsp[0], Bv = pp[16 + s], Cv = pp[24 + s];
  for (int l = 0; l < 2048; l++){
    float dtn = 0.f, xn = 0.f, Bn = 0.f, Cn = 0.f;
    if (l < 2047){
      long long o = (long long)(l + 1);
      dtn = dtp[o * 512]; xn = xsp[o * 256];
      Bn = pp[o * 32 + 16 + s]; Cn = pp[o * 32 + 24 + s];
    }
    float dA = expf(dt * A);
    h = fmaf(dA, h, dt * x * Bv);
    float p = h * Cv;
    p += __shfl_down(p, 4, 8);
    p += __shfl_down(p, 2, 8);
    p += __shfl_down(p, 1, 8);
    if (s == 0){
      float z = zp[(long long)l * 512];
      float y = p + x * Dv;
      xsp[(long long)l * 256] = y * (z / (1.0f + expf(-z)));
    }
    dt = dtn; x = xn; Bv = Bn; Cv = Cn;
  }
}

// ---- layernorm(res + y) in place over y; block absmax -> slot -------------
__global__ __launch_bounds__(256) void ln_kernel(const float* __restrict__ hres,
                                                 float* __restrict__ y,
                                                 const float* __restrict__ g,
                                                 const float* __restrict__ bb,
                                                 float* __restrict__ slot){
  long long row = blockIdx.x;
  int d = threadIdx.x;
  long long o = row * 256 + d;
  float t = hres[o] + y[o];
  __shared__ float red[256];
  red[d] = t; __syncthreads();
  for (int s2 = 128; s2 > 0; s2 >>= 1){
    if (d < s2) red[d] += red[d + s2];
    __syncthreads();
  }
  float m = red[0] * (1.0f / 256.0f);
  __syncthreads();
  float dev = t - m;
  red[d] = dev * dev; __syncthreads();
  for (int s2 = 128; s2 > 0; s2 >>= 1){
    if (d < s2) red[d] += red[d + s2];
    __syncthreads();
  }
  float v = red[0] * (1.0f / 256.0f);
  __syncthreads();
  float out = dev * rsqrtf(v + 1e-5f) * g[d] + bb[d];
  y[o] = out;
  red[d] = fabsf(out); __syncthreads();
  for (int s2 = 128; s2 > 0; s2 >>= 1){
    if (d < s2) red[d] = fmaxf(red[d], red[d + s2]);
    __syncthreads();
  }
  if (d == 0) atomicMax((unsigned int*)slot, __float_as_uint(red[0]));
}

// ---- pooled = mean over L -------------------------------------------------
__global__ __launch_bounds__(256) void mean_kernel(const float* __restrict__ h,
                                                   float* __restrict__ pooled){
  int idx = blockIdx.x * 256 + threadIdx.x;   // 8192
  int d = idx & 255, b = idx >> 8;
  const float* p = h + ((long long)b * 2048) * 256 + d;
  float a0 = 0, a1 = 0, a2 = 0, a3 = 0;
  for (int l = 0; l < 2048; l += 4){
    a0 += p[(long long)l * 256];
    a1 += p[(long long)(l + 1) * 256];
    a2 += p[(long long)(l + 2) * 256];
    a3 += p[(long long)(l + 3) * 256];
  }
  pooled[idx] = (a0 + a1 + a2 + a3) * (1.0f / 2048.0f);
}

// ---- classifier: out[b,n] = pooled[b,:] . clsq[n,:] + cb[n] ---------------
__global__ __launch_bounds__(320) void cls_kernel(const float* __restrict__ pooled,
                                                  const float* __restrict__ clsq,
                                                  const float* __restrict__ cb,
                                                  float* __restrict__ out){
  int tid = threadIdx.x;
  if (tid >= 320) return;
  int b = tid / 10, n = tid - b * 10;
  float acc = cb[n];
  const float* pr = pooled + b * 256;
  const float* wr = clsq + n * 256;
  for (int dd = 0; dd < 256; dd++) acc = fmaf(pr[dd], wr[dd], acc);
  out[tid] = acc;
}

// ===========================================================================
extern "C" void kernel_launch(void* const* d_in, const int* in_sizes, int n_in,
                              void* d_out, int out_size, void* d_ws, size_t ws_size,
                              hipStream_t stream) {
  const float* x_in   = (const float*)d_in[0];   // (32,1,16,4096)
  const float* pw_in  = (const float*)d_in[1];   // (32,1,2,2)
  const float* pb_in  = (const float*)d_in[2];   // (32,)
  const float* pos_in = (const float*)d_in[3];   // (1,2048,256)
  const float* Win    = (const float*)d_in[4];   // (2,2,256,512)
  const float* convw  = (const float*)d_in[5];   // (2,2,256,4)
  const float* convb  = (const float*)d_in[6];   // (2,2,256)
  const float* Wxp    = (const float*)d_in[7];   // (2,2,256,32)
  const float* Wdt    = (const float*)d_in[8];   // (2,2,16,256)
  const float* bdt    = (const float*)d_in[9];   // (2,2,256)
  const float* Alog   = (const float*)d_in[10];  // (2,2,256,8)
  const float* Dskip  = (const float*)d_in[11];  // (2,2,256)
  const float* Wout   = (const float*)d_in[12];  // (2,2,256,256)
  const float* lng    = (const float*)d_in[13];  // (2,256)
  const float* lnb    = (const float*)d_in[14];  // (2,256)
  const float* clsw   = (const float*)d_in[15];  // (10,256)
  const float* clsb   = (const float*)d_in[16];  // (10,)
  float* out = (float*)d_out;

  // -------- workspace layout (floats) --------
  float* W = (float*)d_ws;
  float* sc     = W;               // 64 slots
  float* pwq    = W + 64;          // 128
  float* clsq   = W + 192;         // 2,560
  float* pooled = W + 2752;        // 8,192
  float* posq   = W + 10944;       // 524,288
  float* hbuf   = W + 535232;      // 16,777,216  (64 MB)
  float* ybuf   = hbuf + 16777216; // 16,777,216  (64 MB)
  float* chunkW = ybuf + 16777216; // CB * 1,638,400 floats

  const size_t fixed_f   = 34089664ULL;   // floats used before chunk scratch
  const size_t perseq_f  = 1638400ULL;    // 2048*(512+256+32) floats / sequence
  int CB = 32;
  while (CB > 1 && (fixed_f + (size_t)CB * perseq_f) * 4 > ws_size) CB >>= 1;
  const long long R = (long long)CB * 2048;     // rows per chunk
  float* xz_c   = chunkW;                 // R x 512
  float* xs_c   = xz_c + R * 512;         // R x 256
  float* proj_c = xs_c + R * 256;         // R x 32

  hipMemsetAsync(sc, 0, 64 * sizeof(float), stream);

  // fq(x) scale; fq(patch_w); patchify (inline-fq x) -> hbuf
  absmax_kernel<<<2048, 256, 0, stream>>>(x_in, 2097152LL, sc + 0);
  fq_small<<<1, 256, 0, stream>>>(pw_in, pwq, 128);
  patchify_kernel<<<65536, 256, 0, stream>>>(x_in, pwq, pb_in, hbuf, sc + 0);
  // h = fq(h); h = fq(h)   (literal double-fq as in reference)
  absmax_kernel<<<4096, 256, 0, stream>>>(hbuf, 16777216LL, sc + 1);
  quant_kernel<<<65536, 256, 0, stream>>>(hbuf, hbuf, sc + 1);
  absmax_kernel<<<4096, 256, 0, stream>>>(hbuf, 16777216LL, sc + 2);
  quant_kernel<<<65536, 256, 0, stream>>>(hbuf, hbuf, sc + 2);
  // pos: fq twice -> posq
  absmax_kernel<<<1024, 256, 0, stream>>>(pos_in, 524288LL, sc + 3);
  quant_kernel<<<2048, 256, 0, stream>>>(pos_in, posq, sc + 3);
  absmax_kernel<<<1024, 256, 0, stream>>>(posq, 524288LL, sc + 4);
  quant_kernel<<<2048, 256, 0, stream>>>(posq, posq, sc + 4);
  // h = fq(h + pos)
  addpos_kernel<<<65536, 256, 0, stream>>>(hbuf, posq);
  absmax_kernel<<<4096, 256, 0, stream>>>(hbuf, 16777216LL, sc + 5);
  quant_kernel<<<65536, 256, 0, stream>>>(hbuf, hbuf, sc + 5);

  for (int i = 0; i < 2; i++){
    float* hin = (i == 0) ? hbuf : ybuf;
    float* yac = (i == 0) ? ybuf : hbuf;
    for (int dir = 0; dir < 2; dir++){
      int idx = i * 2 + dir;
      for (int b0 = 0; b0 < 32; b0 += CB){
        const float* hA = hin + (long long)b0 * 524288;
        float*       yC = yac + (long long)b0 * 524288;
        // xz = u(flip?) @ W_in   (R x 512)
        gemm64<<<dim3(8, R / 64), 256, 0, stream>>>(hA, Win + (long long)idx * 131072,
                                                    xz_c, 512, 256, dir, 0, 0);
        // depthwise conv + silu -> xs
        conv_silu_kernel<<<R, 256, 0, stream>>>(xz_c, convw + idx * 1024,
                                                convb + idx * 256, xs_c);
        // proj = xs @ W_xp
        gemm_proj<<<R / 8, 256, 0, stream>>>(xs_c, Wxp + idx * 8192, proj_c);
        // dt -> xz cols [0,256)
        dt_kernel<<<R, 256, 0, stream>>>(proj_c, Wdt + idx * 4096, bdt + idx * 256, xz_c);
        // scan (+ D_skip + silu(z) gate), in place over xs
        scan_kernel<<<CB * 8, 256, 0, stream>>>(xz_c, xs_c, proj_c,
                                                Alog + idx * 2048, Dskip + idx * 256);
        // yac (+=flip) = xs @ W_out   (R x 256)
        gemm64<<<dim3(4, R / 64), 256, 0, stream>>>(xs_c, Wout + (long long)idx * 65536,
                                                    yC, 256, 256, 0, dir, dir);
      }
    }
    // y = fq(yf + yb)
    absmax_kernel<<<4096, 256, 0, stream>>>(yac, 16777216LL, sc + 6 + 2 * i);
    quant_kernel<<<65536, 256, 0, stream>>>(yac, yac, sc + 6 + 2 * i);
    // h_new = fq(layernorm(h + y))  (in place over yac; ping-pong)
    ln_kernel<<<65536, 256, 0, stream>>>(hin, yac, lng + i * 256, lnb + i * 256,
                                         sc + 7 + 2 * i);
    quant_kernel<<<65536, 256, 0, stream>>>(yac, yac, sc + 7 + 2 * i);
  }
  // final hidden is hbuf (layer 1 wrote into hbuf)
  mean_kernel<<<32, 256, 0, stream>>>(hbuf, pooled);
  fq_small<<<1, 256, 0, stream>>>(pooled, pooled, 8192);
  fq_small<<<1, 256, 0, stream>>>(clsw, clsq, 2560);
  cls_kernel<<<1, 320, 0, stream>>>(pooled, clsq, clsb, out);
}

// Round 3
// 7682.885 us; speedup vs baseline: 1.8665x; 1.8665x over previous
//
#include <hip/hip_runtime.h>

// ---------------------------------------------------------------------------
// FEMBA full forward, f32. Shapes (fixed): B=32, L=2048, D=256, di=256, ds=8,
// dtr=16, K=4, nb=2, dirs=2, nc=10.
// Round 3: segment-parallel selective scan (3 passes, 32 segments of 64) +
// absmax/fq fusions into producer epilogues. GEMM unchanged from round 2.
// ---------------------------------------------------------------------------

__device__ __forceinline__ float fq_val(float x, float s){
  float q = rintf(x / s);                 // round-half-even == jnp.round
  q = fminf(fmaxf(q, -128.0f), 127.0f);   // clip(-QMAX-1, QMAX)
  return q * s;
}

__device__ __forceinline__ void block_absmax_atomic(float v, float* slot){
  __shared__ float red[256];
  red[threadIdx.x] = v; __syncthreads();
  for (int s2 = 128; s2 > 0; s2 >>= 1){
    if (threadIdx.x < s2) red[threadIdx.x] = fmaxf(red[threadIdx.x], red[threadIdx.x + s2]);
    __syncthreads();
  }
  if (threadIdx.x == 0) atomicMax((unsigned int*)slot, __float_as_uint(red[0]));
}

// ---- generic absmax (grid) -> atomicMax on float bits --------------------
__global__ __launch_bounds__(256) void absmax_kernel(const float* __restrict__ x,
                                                     long long n, float* __restrict__ slot){
  float m = 0.0f;
  for (long long i = (long long)blockIdx.x * 256 + threadIdx.x; i < n;
       i += (long long)gridDim.x * 256)
    m = fmaxf(m, fabsf(x[i]));
  block_absmax_atomic(m, slot);
}

// ---- quantize; optionally fused absmax of OUTPUT -> oslot ----------------
__global__ __launch_bounds__(256) void quant_kernel(const float* __restrict__ src,
                                                    float* __restrict__ dst,
                                                    const float* __restrict__ slot,
                                                    float* __restrict__ oslot){
  long long i = (long long)blockIdx.x * 256 + threadIdx.x;
  float s = fmaxf(slot[0], 1e-8f) / 127.0f;
  float v = fq_val(src[i], s);
  dst[i] = v;
  if (oslot) block_absmax_atomic(fabsf(v), oslot);
}

// ---- single-block fq for small tensors -----------------------------------
__global__ __launch_bounds__(256) void fq_small(const float* __restrict__ src,
                                                float* __restrict__ dst, int n){
  __shared__ float red[256];
  __shared__ float sS;
  float m = 0.0f;
  for (int i = threadIdx.x; i < n; i += 256) m = fmaxf(m, fabsf(src[i]));
  red[threadIdx.x] = m; __syncthreads();
  for (int s2 = 128; s2 > 0; s2 >>= 1){
    if (threadIdx.x < s2) red[threadIdx.x] = fmaxf(red[threadIdx.x], red[threadIdx.x + s2]);
    __syncthreads();
  }
  if (threadIdx.x == 0) sS = fmaxf(red[0], 1e-8f) / 127.0f;
  __syncthreads();
  float s = sS;
  for (int i = threadIdx.x; i < n; i += 256) dst[i] = fq_val(src[i], s);
}

// ---- patchify + inline fq(x) + fused absmax of result --------------------
__global__ __launch_bounds__(256) void patchify_kernel(const float* __restrict__ x,
                                                       const float* __restrict__ pwq,
                                                       const float* __restrict__ pb,
                                                       float* __restrict__ h,
                                                       const float* __restrict__ slot,
                                                       float* __restrict__ oslot){
  long long idx = (long long)blockIdx.x * 256 + threadIdx.x;  // 16,777,216
  int d = (int)(idx & 255);
  int l = (int)((idx >> 8) & 2047);
  int b = (int)(idx >> 19);
  int c = d & 31, g = d >> 5;
  float s = fmaxf(slot[0], 1e-8f) / 127.0f;
  const float* xp = x + ((long long)(b * 16 + 2 * g) * 4096 + 2 * l);
  float acc = pb[c];
  acc += fq_val(xp[0],    s) * pwq[c * 4 + 0];
  acc += fq_val(xp[1],    s) * pwq[c * 4 + 1];
  acc += fq_val(xp[4096], s) * pwq[c * 4 + 2];
  acc += fq_val(xp[4097], s) * pwq[c * 4 + 3];
  h[idx] = acc;
  block_absmax_atomic(fabsf(acc), oslot);
}

// ---- h += pos (broadcast over batch) + fused absmax ----------------------
__global__ __launch_bounds__(256) void addpos_kernel(float* __restrict__ h,
                                                     const float* __restrict__ pos,
                                                     float* __restrict__ oslot){
  long long i = (long long)blockIdx.x * 256 + threadIdx.x;
  float v = h[i] + pos[i & 524287];
  h[i] = v;
  block_absmax_atomic(fabsf(v), oslot);
}

// ---- tiled fp32 GEMM: C(R,N) = A(R,K)@B(K,N); optional row-flip (within a
//      2048-row sequence) on A read or C write, optional accumulate on C,
//      optional fused absmax of final C values -> slot ----------------------
__global__ __launch_bounds__(256) void gemm64(const float* __restrict__ A,
                                              const float* __restrict__ Bw,
                                              float* __restrict__ C,
                                              int N, int K,
                                              int flipA, int flipC, int accum,
                                              float* __restrict__ slot){
  __shared__ float As[32][68];
  __shared__ float Bs[32][64];
  int tid = threadIdx.x;
  int bn = blockIdx.x, bm = blockIdx.y;
  int tx = tid & 15, ty = tid >> 4;

  int f0 = tid, f1 = tid + 256;
  int ar0 = f0 >> 3, ac0 = (f0 & 7) * 4;
  int ar1 = f1 >> 3, ac1 = (f1 & 7) * 4;
  int am0 = bm * 64 + ar0, am1 = bm * 64 + ar1;
  long long amr0 = flipA ? (((long long)(am0 >> 11)) << 11) + (2047 - (am0 & 2047)) : am0;
  long long amr1 = flipA ? (((long long)(am1 >> 11)) << 11) + (2047 - (am1 & 2047)) : am1;
  const float* Ap0 = A + amr0 * (long long)K + ac0;
  const float* Ap1 = A + amr1 * (long long)K + ac1;
  int br0 = f0 >> 4, bc0 = (f0 & 15) * 4;
  int br1 = f1 >> 4, bc1 = (f1 & 15) * 4;
  const float* Bp0 = Bw + (long long)br0 * N + bn * 64 + bc0;
  const float* Bp1 = Bw + (long long)br1 * N + bn * 64 + bc1;

  float acc[4][4] = {};
  for (int k0 = 0; k0 < K; k0 += 32){
    float4 a0v = *(const float4*)(Ap0 + k0);
    float4 a1v = *(const float4*)(Ap1 + k0);
    float4 b0v = *(const float4*)(Bp0 + (long long)k0 * N);
    float4 b1v = *(const float4*)(Bp1 + (long long)k0 * N);
    As[ac0 + 0][ar0] = a0v.x; As[ac0 + 1][ar0] = a0v.y;
    As[ac0 + 2][ar0] = a0v.z; As[ac0 + 3][ar0] = a0v.w;
    As[ac1 + 0][ar1] = a1v.x; As[ac1 + 1][ar1] = a1v.y;
    As[ac1 + 2][ar1] = a1v.z; As[ac1 + 3][ar1] = a1v.w;
    *(float4*)&Bs[br0][bc0] = b0v;
    *(float4*)&Bs[br1][bc1] = b1v;
    __syncthreads();
#pragma unroll
    for (int kk = 0; kk < 32; kk++){
      float4 av = *(const float4*)&As[kk][ty * 4];
      float4 bv = *(const float4*)&Bs[kk][tx * 4];
      float ar[4] = {av.x, av.y, av.z, av.w};
      float br[4] = {bv.x, bv.y, bv.z, bv.w};
#pragma unroll
      for (int i = 0; i < 4; i++)
#pragma unroll
        for (int j = 0; j < 4; j++)
          acc[i][j] = fmaf(ar[i], br[j], acc[i][j]);
    }
    __syncthreads();
  }
  float mx = 0.0f;
#pragma unroll
  for (int i = 0; i < 4; i++){
    int m = bm * 64 + ty * 4 + i;
    long long mr = flipC ? (((long long)(m >> 11)) << 11) + (2047 - (m & 2047)) : m;
    float* Cp = C + mr * (long long)N + bn * 64 + tx * 4;
    if (accum){
#pragma unroll
      for (int j = 0; j < 4; j++){
        float v = Cp[j] + acc[i][j];
        Cp[j] = v;
        mx = fmaxf(mx, fabsf(v));
      }
    } else {
      float4 v = make_float4(acc[i][0], acc[i][1], acc[i][2], acc[i][3]);
      *(float4*)Cp = v;
    }
  }
  if (slot) block_absmax_atomic(mx, slot);
}

// ---- depthwise causal conv (K=4) + SiLU ----------------------------------
__global__ __launch_bounds__(256) void conv_silu_kernel(const float* __restrict__ xz,
                                                        const float* __restrict__ cw,
                                                        const float* __restrict__ cb,
                                                        float* __restrict__ xs){
  long long idx = (long long)blockIdx.x * 256 + threadIdx.x;
  int d = (int)(idx & 255);
  long long bl = idx >> 8;
  int l = (int)(bl & 2047);
  const float* base = xz + (bl << 9) + d;   // row stride 512
  float w0 = cw[d*4], w1 = cw[d*4+1], w2 = cw[d*4+2], w3 = cw[d*4+3];
  float acc = cb[d] + w3 * base[0];
  if (l >= 1) acc += w2 * base[-512];
  if (l >= 2) acc += w1 * base[-1024];
  if (l >= 3) acc += w0 * base[-1536];
  xs[idx] = acc / (1.0f + expf(-acc));      // silu
}

// ---- proj = xs @ W_xp (K=256, N=32); 8 rows per block ---------------------
__global__ __launch_bounds__(256) void gemm_proj(const float* __restrict__ xs,
                                                 const float* __restrict__ W,
                                                 float* __restrict__ proj){
  __shared__ float As[2048];
  long long row0 = (long long)blockIdx.x * 8;
  for (int i = threadIdx.x; i < 2048; i += 256) As[i] = xs[row0 * 256 + i];
  __syncthreads();
  int r = threadIdx.x >> 5, cidx = threadIdx.x & 31;
  float acc = 0.0f;
#pragma unroll 8
  for (int k = 0; k < 256; k++) acc = fmaf(As[r * 256 + k], W[k * 32 + cidx], acc);
  proj[(row0 + r) * 32 + cidx] = acc;
}

// ---- dt = softplus(proj[:, :16] @ W_dt + b_dt) -> xz cols [0,256) ---------
__global__ __launch_bounds__(256) void dt_kernel(const float* __restrict__ proj,
                                                 const float* __restrict__ Wdt,
                                                 const float* __restrict__ bdt,
                                                 float* __restrict__ dtbuf){
  __shared__ float pr[16];
  long long row = blockIdx.x;
  if (threadIdx.x < 16) pr[threadIdx.x] = proj[row * 32 + threadIdx.x];
  __syncthreads();
  int d = threadIdx.x;
  float acc = bdt[d];
#pragma unroll
  for (int r = 0; r < 16; r++) acc = fmaf(pr[r], Wdt[r * 256 + d], acc);
  float sp = (acc > 0.0f) ? acc + log1pf(expf(-acc)) : log1pf(expf(acc));
  dtbuf[row * 512 + d] = sp;
}

// ===== segment-parallel selective scan: L=2048 -> 32 segments of 64 ========
// thread map (scan1/scan3): t = b*65536 + seg*2048 + d*8 + s
// scan1: per-segment (P = prod dA, q = scan with h0=0)
__global__ __launch_bounds__(256) void scan1_kernel(const float* __restrict__ xzb,
                                                    const float* __restrict__ xs,
                                                    const float* __restrict__ proj,
                                                    const float* __restrict__ A_log,
                                                    float* __restrict__ Pb,
                                                    float* __restrict__ Qb){
  int t = blockIdx.x * 256 + threadIdx.x;
  int s = t & 7;
  int d = (t >> 3) & 255;
  int seg = (t >> 11) & 31;
  int b = t >> 16;
  float A = -expf(A_log[d * 8 + s]);
  long long rowbase = (long long)b * 2048 + seg * 64;
  const float* dtp = xzb + rowbase * 512 + d;
  const float* xp  = xs  + rowbase * 256 + d;
  const float* pp  = proj + rowbase * 32;
  float P = 1.0f, q = 0.0f;
#pragma unroll 4
  for (int l = 0; l < 64; l++){
    float dt = dtp[(long long)l * 512];
    float x  = xp[(long long)l * 256];
    float Bv = pp[l * 32 + 16 + s];
    float dA = expf(dt * A);
    P *= dA;
    q = fmaf(dA, q, dt * x * Bv);
  }
  Pb[t] = P; Qb[t] = q;
}

// scan2: serial prefix over segments; Hs[seg] = h at segment start
__global__ __launch_bounds__(256) void scan2_kernel(const float* __restrict__ Pb,
                                                    const float* __restrict__ Qb,
                                                    float* __restrict__ Hs){
  int t = blockIdx.x * 256 + threadIdx.x;  // CB*2048: (b, d*8+s)
  int ds_ = t & 2047;
  int b = t >> 11;
  float h = 0.0f;
#pragma unroll
  for (int g = 0; g < 32; g++){
    long long idx = (((long long)b * 32 + g) << 11) + ds_;
    Hs[idx] = h;
    h = fmaf(Pb[idx], h, Qb[idx]);
  }
}

// scan3: recompute with correct h_start, reduce over s, gate, write y in xs
__global__ __launch_bounds__(256) void scan3_kernel(const float* __restrict__ xzb,
                                                    float* __restrict__ xs,
                                                    const float* __restrict__ proj,
                                                    const float* __restrict__ A_log,
                                                    const float* __restrict__ Dsk,
                                                    const float* __restrict__ Hs){
  int t = blockIdx.x * 256 + threadIdx.x;
  int s = t & 7;
  int d = (t >> 3) & 255;
  int seg = (t >> 11) & 31;
  int b = t >> 16;
  float A = -expf(A_log[d * 8 + s]);
  float Dv = Dsk[d];
  float h = Hs[t];
  long long rowbase = (long long)b * 2048 + seg * 64;
  const float* dtp = xzb + rowbase * 512 + d;
  const float* zp  = dtp + 256;
  float* xsp = xs + rowbase * 256 + d;
  const float* pp = proj + rowbase * 32;
  for (int l = 0; l < 64; l++){
    float dt = dtp[(long long)l * 512];
    float x  = xsp[(long long)l * 256];
    float Bv = pp[l * 32 + 16 + s];
    float Cv = pp[l * 32 + 24 + s];
    float dA = expf(dt * A);
    h = fmaf(dA, h, dt * x * Bv);
    float p = h * Cv;
    p += __shfl_down(p, 4, 8);
    p += __shfl_down(p, 2, 8);
    p += __shfl_down(p, 1, 8);
    if (s == 0){
      float z = zp[(long long)l * 512];
      float y = p + x * Dv;
      xsp[(long long)l * 256] = y * (z / (1.0f + expf(-z)));
    }
  }
}

// ---- layernorm(res + fq(y)) in place over y; block absmax -> slot ---------
__global__ __launch_bounds__(256) void ln_kernel(const float* __restrict__ hres,
                                                 float* __restrict__ y,
                                                 const float* __restrict__ g,
                                                 const float* __restrict__ bb,
                                                 const float* __restrict__ slot_y,
                                                 float* __restrict__ slot){
  long long row = blockIdx.x;
  int d = threadIdx.x;
  long long o = row * 256 + d;
  float sy = fmaxf(slot_y[0], 1e-8f) / 127.0f;
  float t = hres[o] + fq_val(y[o], sy);
  __shared__ float red[256];
  red[d] = t; __syncthreads();
  for (int s2 = 128; s2 > 0; s2 >>= 1){
    if (d < s2) red[d] += red[d + s2];
    __syncthreads();
  }
  float m = red[0] * (1.0f / 256.0f);
  __syncthreads();
  float dev = t - m;
  red[d] = dev * dev; __syncthreads();
  for (int s2 = 128; s2 > 0; s2 >>= 1){
    if (d < s2) red[d] += red[d + s2];
    __syncthreads();
  }
  float v = red[0] * (1.0f / 256.0f);
  __syncthreads();
  float outv = dev * rsqrtf(v + 1e-5f) * g[d] + bb[d];
  y[o] = outv;
  red[d] = fabsf(outv); __syncthreads();
  for (int s2 = 128; s2 > 0; s2 >>= 1){
    if (d < s2) red[d] = fmaxf(red[d], red[d + s2]);
    __syncthreads();
  }
  if (d == 0) atomicMax((unsigned int*)slot, __float_as_uint(red[0]));
}

// ---- pooled = mean over L -------------------------------------------------
__global__ __launch_bounds__(256) void mean_kernel(const float* __restrict__ h,
                                                   float* __restrict__ pooled){
  int idx = blockIdx.x * 256 + threadIdx.x;   // 8192
  int d = idx & 255, b = idx >> 8;
  const float* p = h + ((long long)b * 2048) * 256 + d;
  float a0 = 0, a1 = 0, a2 = 0, a3 = 0;
  for (int l = 0; l < 2048; l += 4){
    a0 += p[(long long)l * 256];
    a1 += p[(long long)(l + 1) * 256];
    a2 += p[(long long)(l + 2) * 256];
    a3 += p[(long long)(l + 3) * 256];
  }
  pooled[idx] = (a0 + a1 + a2 + a3) * (1.0f / 2048.0f);
}

// ---- classifier -----------------------------------------------------------
__global__ __launch_bounds__(320) void cls_kernel(const float* __restrict__ pooled,
                                                  const float* __restrict__ clsq,
                                                  const float* __restrict__ cb,
                                                  float* __restrict__ out){
  int tid = threadIdx.x;
  if (tid >= 320) return;
  int b = tid / 10, n = tid - b * 10;
  float acc = cb[n];
  const float* pr = pooled + b * 256;
  const float* wr = clsq + n * 256;
  for (int dd = 0; dd < 256; dd++) acc = fmaf(pr[dd], wr[dd], acc);
  out[tid] = acc;
}

// ===========================================================================
extern "C" void kernel_launch(void* const* d_in, const int* in_sizes, int n_in,
                              void* d_out, int out_size, void* d_ws, size_t ws_size,
                              hipStream_t stream) {
  const float* x_in   = (const float*)d_in[0];
  const float* pw_in  = (const float*)d_in[1];
  const float* pb_in  = (const float*)d_in[2];
  const float* pos_in = (const float*)d_in[3];
  const float* Win    = (const float*)d_in[4];
  const float* convw  = (const float*)d_in[5];
  const float* convb  = (const float*)d_in[6];
  const float* Wxp    = (const float*)d_in[7];
  const float* Wdt    = (const float*)d_in[8];
  const float* bdt    = (const float*)d_in[9];
  const float* Alog   = (const float*)d_in[10];
  const float* Dskip  = (const float*)d_in[11];
  const float* Wout   = (const float*)d_in[12];
  const float* lng    = (const float*)d_in[13];
  const float* lnb    = (const float*)d_in[14];
  const float* clsw   = (const float*)d_in[15];
  const float* clsb   = (const float*)d_in[16];
  float* out = (float*)d_out;

  // -------- workspace layout (floats) --------
  float* W = (float*)d_ws;
  float* sc     = W;               // 64 slots
  float* pwq    = W + 64;          // 128
  float* clsq   = W + 192;         // 2,560
  float* pooled = W + 2752;        // 8,192
  float* posq   = W + 10944;       // 524,288
  float* hbuf   = W + 535232;      // 16,777,216  (64 MB)
  float* ybuf   = hbuf + 16777216; // 16,777,216  (64 MB)
  float* chunkW = ybuf + 16777216; // CB * perseq_f floats

  const size_t fixed_f  = 34089664ULL;
  const size_t perseq_f = 1835008ULL;  // 2048*(512+256+32) + 3*65536
  int CB = 32;
  while (CB > 1 && (fixed_f + (size_t)CB * perseq_f) * 4 > ws_size) CB >>= 1;
  const long long R = (long long)CB * 2048;
  float* xz_c   = chunkW;                 // R x 512
  float* xs_c   = xz_c + R * 512;         // R x 256
  float* proj_c = xs_c + R * 256;         // R x 32
  float* Pb_c   = proj_c + R * 32;        // CB * 65536
  float* Qb_c   = Pb_c + (long long)CB * 65536;
  float* Hs_c   = Qb_c + (long long)CB * 65536;

  hipMemsetAsync(sc, 0, 64 * sizeof(float), stream);

  // fq(x) scale; fq(patch_w); patchify (inline-fq x, fused absmax) -> hbuf
  absmax_kernel<<<2048, 256, 0, stream>>>(x_in, 2097152LL, sc + 0);
  fq_small<<<1, 256, 0, stream>>>(pw_in, pwq, 128);
  patchify_kernel<<<65536, 256, 0, stream>>>(x_in, pwq, pb_in, hbuf, sc + 0, sc + 1);
  // h = fq(h) (fused absmax of output); h = fq(h)
  quant_kernel<<<65536, 256, 0, stream>>>(hbuf, hbuf, sc + 1, sc + 2);
  quant_kernel<<<65536, 256, 0, stream>>>(hbuf, hbuf, sc + 2, nullptr);
  // pos: fq twice -> posq
  absmax_kernel<<<1024, 256, 0, stream>>>(pos_in, 524288LL, sc + 3);
  quant_kernel<<<2048, 256, 0, stream>>>(pos_in, posq, sc + 3, sc + 4);
  quant_kernel<<<2048, 256, 0, stream>>>(posq, posq, sc + 4, nullptr);
  // h = fq(h + pos) (add fused with absmax)
  addpos_kernel<<<65536, 256, 0, stream>>>(hbuf, posq, sc + 5);
  quant_kernel<<<65536, 256, 0, stream>>>(hbuf, hbuf, sc + 5, nullptr);

  for (int i = 0; i < 2; i++){
    float* hin = (i == 0) ? hbuf : ybuf;
    float* yac = (i == 0) ? ybuf : hbuf;
    for (int dir = 0; dir < 2; dir++){
      int idx = i * 2 + dir;
      for (int b0 = 0; b0 < 32; b0 += CB){
        const float* hA = hin + (long long)b0 * 524288;
        float*       yC = yac + (long long)b0 * 524288;
        // xz = u(flip?) @ W_in   (R x 512)
        gemm64<<<dim3(8, R / 64), 256, 0, stream>>>(hA, Win + (long long)idx * 131072,
                                                    xz_c, 512, 256, dir, 0, 0, nullptr);
        // depthwise conv + silu -> xs
        conv_silu_kernel<<<R, 256, 0, stream>>>(xz_c, convw + idx * 1024,
                                                convb + idx * 256, xs_c);
        // proj = xs @ W_xp
        gemm_proj<<<R / 8, 256, 0, stream>>>(xs_c, Wxp + idx * 8192, proj_c);
        // dt -> xz cols [0,256)
        dt_kernel<<<R, 256, 0, stream>>>(proj_c, Wdt + idx * 4096, bdt + idx * 256, xz_c);
        // segment-parallel scan (+ D_skip + silu(z) gate), in place over xs
        scan1_kernel<<<CB * 256, 256, 0, stream>>>(xz_c, xs_c, proj_c,
                                                   Alog + idx * 2048, Pb_c, Qb_c);
        scan2_kernel<<<CB * 8, 256, 0, stream>>>(Pb_c, Qb_c, Hs_c);
        scan3_kernel<<<CB * 256, 256, 0, stream>>>(xz_c, xs_c, proj_c,
                                                   Alog + idx * 2048,
                                                   Dskip + idx * 256, Hs_c);
        // yac (+=flip) = xs @ W_out (R x 256); dir1 fuses absmax(yf+yb)
        gemm64<<<dim3(4, R / 64), 256, 0, stream>>>(xs_c, Wout + (long long)idx * 65536,
                                                    yC, 256, 256, 0, dir, dir,
                                                    dir ? (sc + 6 + 2 * i) : nullptr);
      }
    }
    // h_new = fq(layernorm(h + fq(y)))  (fq(y) fused into LN input)
    ln_kernel<<<65536, 256, 0, stream>>>(hin, yac, lng + i * 256, lnb + i * 256,
                                         sc + 6 + 2 * i, sc + 7 + 2 * i);
    quant_kernel<<<65536, 256, 0, stream>>>(yac, yac, sc + 7 + 2 * i, nullptr);
  }
  // final hidden is hbuf
  mean_kernel<<<32, 256, 0, stream>>>(hbuf, pooled);
  fq_small<<<1, 256, 0, stream>>>(pooled, pooled, 8192);
  fq_small<<<1, 256, 0, stream>>>(clsw, clsq, 2560);
  cls_kernel<<<1, 320, 0, stream>>>(pooled, clsq, clsb, out);
}

// Round 4
// 4159.781 us; speedup vs baseline: 3.4474x; 1.8469x over previous
//
#include <hip/hip_runtime.h>

// ---------------------------------------------------------------------------
// FEMBA full forward, f32. Shapes (fixed): B=32, L=2048, D=256, di=256, ds=8,
// dtr=16, K=4, nb=2, dirs=2, nc=10.
// Round 4: wave-shuffle reductions, bucketed absmax atomics (64 spread slots
// + combine kernel), quantize-on-read at consumers (no standalone quant
// passes; scale chains via device-side chain kernel using monotonicity of fq).
// ---------------------------------------------------------------------------

__device__ __forceinline__ float fq_val(float x, float s){
  float q = rintf(x / s);                 // round-half-even == jnp.round
  q = fminf(fmaxf(q, -128.0f), 127.0f);   // clip(-QMAX-1, QMAX)
  return q * s;
}

__device__ __forceinline__ float g_of(float a){ return fmaxf(a, 1e-8f) / 127.0f; }

// block absmax -> one atomic per block into spread bucket (blockDim==256)
__device__ __forceinline__ void bk_absmax(float v, float* bkt){
  for (int m = 32; m; m >>= 1) v = fmaxf(v, __shfl_xor(v, m));
  __shared__ float wmax[4];
  int lane = threadIdx.x & 63, wid = threadIdx.x >> 6;
  if (lane == 0) wmax[wid] = v;
  __syncthreads();
  if (threadIdx.x == 0){
    float m = fmaxf(fmaxf(wmax[0], wmax[1]), fmaxf(wmax[2], wmax[3]));
    atomicMax((unsigned int*)&bkt[(blockIdx.x & 63) * 16], __float_as_uint(m));
  }
}

// ---- grid absmax -> buckets ----------------------------------------------
__global__ __launch_bounds__(256) void absmax_b(const float* __restrict__ x,
                                                long long n, float* __restrict__ bkt){
  float m = 0.0f;
  for (long long i = (long long)blockIdx.x * 256 + threadIdx.x; i < n;
       i += (long long)gridDim.x * 256)
    m = fmaxf(m, fabsf(x[i]));
  bk_absmax(m, bkt);
}

// ---- fold 64 buckets -> one slot -----------------------------------------
__global__ __launch_bounds__(64) void combine_kernel(const float* __restrict__ bkt,
                                                     float* __restrict__ slot){
  float v = bkt[(threadIdx.x & 63) * 16];
  for (int m = 32; m; m >>= 1) v = fmaxf(v, __shfl_xor(v, m));
  if (threadIdx.x == 0) slot[0] = v;
}

// ---- scale chain for the double-fq of h and pos (fq monotone+odd =>
//      absmax(fq(X,s)) == fq(absmax(X),s)) ----------------------------------
__global__ __launch_bounds__(64) void chain_kernel(float* __restrict__ sc){
  if (threadIdx.x == 0){
    float s1 = g_of(sc[1]);               // h0 fq#1 scale
    float a1 = fq_val(sc[1], s1);
    sc[2] = s1; sc[3] = g_of(a1);         // h0 fq#2 scale
    float p1 = g_of(sc[4]);               // pos fq#1 scale
    float a2 = fq_val(sc[4], p1);
    sc[5] = p1; sc[6] = g_of(a2);         // pos fq#2 scale
  }
}

// ---- single-block fq for small tensors -----------------------------------
__global__ __launch_bounds__(256) void fq_small(const float* __restrict__ src,
                                                float* __restrict__ dst, int n){
  __shared__ float red[256];
  __shared__ float sS;
  float m = 0.0f;
  for (int i = threadIdx.x; i < n; i += 256) m = fmaxf(m, fabsf(src[i]));
  red[threadIdx.x] = m; __syncthreads();
  for (int s2 = 128; s2 > 0; s2 >>= 1){
    if (threadIdx.x < s2) red[threadIdx.x] = fmaxf(red[threadIdx.x], red[threadIdx.x + s2]);
    __syncthreads();
  }
  if (threadIdx.x == 0) sS = g_of(red[0]);
  __syncthreads();
  float s = sS;
  for (int i = threadIdx.x; i < n; i += 256) dst[i] = fq_val(src[i], s);
}

// ---- patchify (x4 vectorized) + inline fq(x) + bucketed absmax ------------
__global__ __launch_bounds__(256) void patchify_kernel(const float* __restrict__ x,
                                                       const float* __restrict__ pwq,
                                                       const float* __restrict__ pb,
                                                       float* __restrict__ h,
                                                       const float* __restrict__ slot,
                                                       float* __restrict__ bkt){
  int t = blockIdx.x * 256 + threadIdx.x;   // 4,194,304
  int q = t & 63;                            // d/4
  int l = (t >> 6) & 2047;
  int b = t >> 17;
  int d0 = q * 4;
  int c0 = d0 & 31, g = d0 >> 5;
  float s = g_of(slot[0]);
  const float* xp = x + ((long long)(b * 16 + 2 * g) * 4096 + 2 * l);
  float x0 = fq_val(xp[0], s),    x1 = fq_val(xp[1], s);
  float x2 = fq_val(xp[4096], s), x3 = fq_val(xp[4097], s);
  float4 o; float* op = (float*)&o;
  float mx = 0.0f;
#pragma unroll
  for (int j = 0; j < 4; j++){
    int c = c0 + j;
    float a = pb[c] + x0 * pwq[c * 4] + x1 * pwq[c * 4 + 1]
                    + x2 * pwq[c * 4 + 2] + x3 * pwq[c * 4 + 3];
    op[j] = a; mx = fmaxf(mx, fabsf(a));
  }
  *(float4*)(h + (long long)t * 4) = o;
  bk_absmax(mx, bkt);
}

// ---- h = fq(fq(h)) + fq(fq(pos)), raw sum written; bucketed absmax --------
__global__ __launch_bounds__(256) void addpos_kernel(float* __restrict__ h,
                                                     const float* __restrict__ pos,
                                                     const float* __restrict__ sc,
                                                     float* __restrict__ bkt){
  long long t = (long long)blockIdx.x * 256 + threadIdx.x;  // 4,194,304
  float s1 = sc[2], s2 = sc[3], p1 = sc[5], p2 = sc[6];     // scales (chain)
  float4 hv = *(const float4*)(h + t * 4);
  float4 pv = *(const float4*)(pos + ((t * 4) & 524287));
  float* hp = (float*)&hv; float* pp = (float*)&pv;
  float4 o; float* op = (float*)&o;
  float mx = 0.0f;
#pragma unroll
  for (int j = 0; j < 4; j++){
    float v = fq_val(fq_val(hp[j], s1), s2) + fq_val(fq_val(pp[j], p1), p2);
    op[j] = v; mx = fmaxf(mx, fabsf(v));
  }
  *(float4*)(h + t * 4) = o;
  bk_absmax(mx, bkt);
}

// ---- tiled fp32 GEMM: C(R,N) = fqA(A)(R,K)@B(K,N); optional row-flip on A
//      read or C write (within 2048-row sequences), optional accumulate,
//      optional fq-on-read of A (aslot=absmax), optional bucketed absmax ----
__global__ __launch_bounds__(256) void gemm64(const float* __restrict__ A,
                                              const float* __restrict__ Bw,
                                              float* __restrict__ C,
                                              int N, int K,
                                              int flipA, int flipC, int accum,
                                              const float* __restrict__ aslot,
                                              float* __restrict__ bkt){
  __shared__ float As[32][68];
  __shared__ float Bs[32][64];
  int tid = threadIdx.x;
  int bn = blockIdx.x, bm = blockIdx.y;
  int tx = tid & 15, ty = tid >> 4;
  float sA = aslot ? g_of(aslot[0]) : 0.0f;

  int f0 = tid, f1 = tid + 256;
  int ar0 = f0 >> 3, ac0 = (f0 & 7) * 4;
  int ar1 = f1 >> 3, ac1 = (f1 & 7) * 4;
  int am0 = bm * 64 + ar0, am1 = bm * 64 + ar1;
  long long amr0 = flipA ? (((long long)(am0 >> 11)) << 11) + (2047 - (am0 & 2047)) : am0;
  long long amr1 = flipA ? (((long long)(am1 >> 11)) << 11) + (2047 - (am1 & 2047)) : am1;
  const float* Ap0 = A + amr0 * (long long)K + ac0;
  const float* Ap1 = A + amr1 * (long long)K + ac1;
  int br0 = f0 >> 4, bc0 = (f0 & 15) * 4;
  int br1 = f1 >> 4, bc1 = (f1 & 15) * 4;
  const float* Bp0 = Bw + (long long)br0 * N + bn * 64 + bc0;
  const float* Bp1 = Bw + (long long)br1 * N + bn * 64 + bc1;

  float acc[4][4] = {};
  for (int k0 = 0; k0 < K; k0 += 32){
    float4 a0v = *(const float4*)(Ap0 + k0);
    float4 a1v = *(const float4*)(Ap1 + k0);
    float4 b0v = *(const float4*)(Bp0 + (long long)k0 * N);
    float4 b1v = *(const float4*)(Bp1 + (long long)k0 * N);
    if (aslot){
      a0v.x = fq_val(a0v.x, sA); a0v.y = fq_val(a0v.y, sA);
      a0v.z = fq_val(a0v.z, sA); a0v.w = fq_val(a0v.w, sA);
      a1v.x = fq_val(a1v.x, sA); a1v.y = fq_val(a1v.y, sA);
      a1v.z = fq_val(a1v.z, sA); a1v.w = fq_val(a1v.w, sA);
    }
    As[ac0 + 0][ar0] = a0v.x; As[ac0 + 1][ar0] = a0v.y;
    As[ac0 + 2][ar0] = a0v.z; As[ac0 + 3][ar0] = a0v.w;
    As[ac1 + 0][ar1] = a1v.x; As[ac1 + 1][ar1] = a1v.y;
    As[ac1 + 2][ar1] = a1v.z; As[ac1 + 3][ar1] = a1v.w;
    *(float4*)&Bs[br0][bc0] = b0v;
    *(float4*)&Bs[br1][bc1] = b1v;
    __syncthreads();
#pragma unroll
    for (int kk = 0; kk < 32; kk++){
      float4 av = *(const float4*)&As[kk][ty * 4];
      float4 bv = *(const float4*)&Bs[kk][tx * 4];
      float ar[4] = {av.x, av.y, av.z, av.w};
      float br[4] = {bv.x, bv.y, bv.z, bv.w};
#pragma unroll
      for (int i = 0; i < 4; i++)
#pragma unroll
        for (int j = 0; j < 4; j++)
          acc[i][j] = fmaf(ar[i], br[j], acc[i][j]);
    }
    __syncthreads();
  }
  float mx = 0.0f;
#pragma unroll
  for (int i = 0; i < 4; i++){
    int m = bm * 64 + ty * 4 + i;
    long long mr = flipC ? (((long long)(m >> 11)) << 11) + (2047 - (m & 2047)) : m;
    float* Cp = C + mr * (long long)N + bn * 64 + tx * 4;
    if (accum){
#pragma unroll
      for (int j = 0; j < 4; j++){
        float v = Cp[j] + acc[i][j];
        Cp[j] = v;
        mx = fmaxf(mx, fabsf(v));
      }
    } else {
      float4 v = make_float4(acc[i][0], acc[i][1], acc[i][2], acc[i][3]);
      *(float4*)Cp = v;
    }
  }
  if (bkt) bk_absmax(mx, bkt);
}

// ---- depthwise causal conv (K=4) + SiLU ----------------------------------
__global__ __launch_bounds__(256) void conv_silu_kernel(const float* __restrict__ xz,
                                                        const float* __restrict__ cw,
                                                        const float* __restrict__ cb,
                                                        float* __restrict__ xs){
  long long idx = (long long)blockIdx.x * 256 + threadIdx.x;
  int d = (int)(idx & 255);
  long long bl = idx >> 8;
  int l = (int)(bl & 2047);
  const float* base = xz + (bl << 9) + d;   // row stride 512
  float w0 = cw[d*4], w1 = cw[d*4+1], w2 = cw[d*4+2], w3 = cw[d*4+3];
  float acc = cb[d] + w3 * base[0];
  if (l >= 1) acc += w2 * base[-512];
  if (l >= 2) acc += w1 * base[-1024];
  if (l >= 3) acc += w0 * base[-1536];
  xs[idx] = acc / (1.0f + expf(-acc));      // silu
}

// ---- proj = xs @ W_xp (K=256, N=32); 8 rows per block ---------------------
__global__ __launch_bounds__(256) void gemm_proj(const float* __restrict__ xs,
                                                 const float* __restrict__ W,
                                                 float* __restrict__ proj){
  __shared__ float As[2048];
  long long row0 = (long long)blockIdx.x * 8;
  for (int i = threadIdx.x; i < 2048; i += 256) As[i] = xs[row0 * 256 + i];
  __syncthreads();
  int r = threadIdx.x >> 5, cidx = threadIdx.x & 31;
  float acc = 0.0f;
#pragma unroll 8
  for (int k = 0; k < 256; k++) acc = fmaf(As[r * 256 + k], W[k * 32 + cidx], acc);
  proj[(row0 + r) * 32 + cidx] = acc;
}

// ---- dt = softplus(proj[:, :16] @ W_dt + b_dt) -> xz cols [0,256) ---------
__global__ __launch_bounds__(256) void dt_kernel(const float* __restrict__ proj,
                                                 const float* __restrict__ Wdt,
                                                 const float* __restrict__ bdt,
                                                 float* __restrict__ dtbuf){
  __shared__ float pr[16];
  long long row = blockIdx.x;
  if (threadIdx.x < 16) pr[threadIdx.x] = proj[row * 32 + threadIdx.x];
  __syncthreads();
  int d = threadIdx.x;
  float acc = bdt[d];
#pragma unroll
  for (int r = 0; r < 16; r++) acc = fmaf(pr[r], Wdt[r * 256 + d], acc);
  float sp = (acc > 0.0f) ? acc + log1pf(expf(-acc)) : log1pf(expf(acc));
  dtbuf[row * 512 + d] = sp;
}

// ===== segment-parallel selective scan: L=2048 -> 32 segments of 64 ========
__global__ __launch_bounds__(256) void scan1_kernel(const float* __restrict__ xzb,
                                                    const float* __restrict__ xs,
                                                    const float* __restrict__ proj,
                                                    const float* __restrict__ A_log,
                                                    float* __restrict__ Pb,
                                                    float* __restrict__ Qb){
  int t = blockIdx.x * 256 + threadIdx.x;
  int s = t & 7;
  int d = (t >> 3) & 255;
  int seg = (t >> 11) & 31;
  int b = t >> 16;
  float A = -expf(A_log[d * 8 + s]);
  long long rowbase = (long long)b * 2048 + seg * 64;
  const float* dtp = xzb + rowbase * 512 + d;
  const float* xp  = xs  + rowbase * 256 + d;
  const float* pp  = proj + rowbase * 32;
  float P = 1.0f, q = 0.0f;
#pragma unroll 4
  for (int l = 0; l < 64; l++){
    float dt = dtp[(long long)l * 512];
    float x  = xp[(long long)l * 256];
    float Bv = pp[l * 32 + 16 + s];
    float dA = expf(dt * A);
    P *= dA;
    q = fmaf(dA, q, dt * x * Bv);
  }
  Pb[t] = P; Qb[t] = q;
}

__global__ __launch_bounds__(256) void scan2_kernel(const float* __restrict__ Pb,
                                                    const float* __restrict__ Qb,
                                                    float* __restrict__ Hs){
  int t = blockIdx.x * 256 + threadIdx.x;  // CB*2048: (b, d*8+s)
  int ds_ = t & 2047;
  int b = t >> 11;
  float h = 0.0f;
#pragma unroll
  for (int g = 0; g < 32; g++){
    long long idx = (((long long)b * 32 + g) << 11) + ds_;
    Hs[idx] = h;
    h = fmaf(Pb[idx], h, Qb[idx]);
  }
}

__global__ __launch_bounds__(256) void scan3_kernel(const float* __restrict__ xzb,
                                                    float* __restrict__ xs,
                                                    const float* __restrict__ proj,
                                                    const float* __restrict__ A_log,
                                                    const float* __restrict__ Dsk,
                                                    const float* __restrict__ Hs){
  int t = blockIdx.x * 256 + threadIdx.x;
  int s = t & 7;
  int d = (t >> 3) & 255;
  int seg = (t >> 11) & 31;
  int b = t >> 16;
  float A = -expf(A_log[d * 8 + s]);
  float Dv = Dsk[d];
  float h = Hs[t];
  long long rowbase = (long long)b * 2048 + seg * 64;
  const float* dtp = xzb + rowbase * 512 + d;
  const float* zp  = dtp + 256;
  float* xsp = xs + rowbase * 256 + d;
  const float* pp = proj + rowbase * 32;
  for (int l = 0; l < 64; l++){
    float dt = dtp[(long long)l * 512];
    float x  = xsp[(long long)l * 256];
    float Bv = pp[l * 32 + 16 + s];
    float Cv = pp[l * 32 + 24 + s];
    float dA = expf(dt * A);
    h = fmaf(dA, h, dt * x * Bv);
    float p = h * Cv;
    p += __shfl_down(p, 4, 8);
    p += __shfl_down(p, 2, 8);
    p += __shfl_down(p, 1, 8);
    if (s == 0){
      float z = zp[(long long)l * 512];
      float y = p + x * Dv;
      xsp[(long long)l * 256] = y * (z / (1.0f + expf(-z)));
    }
  }
}

// ---- layernorm(fq(hres) + fq(y)) : one row per wave, shfl-only ------------
__global__ __launch_bounds__(256) void ln_kernel(const float* __restrict__ hraw,
                                                 const float* __restrict__ hslot,
                                                 float* __restrict__ y,
                                                 const float* __restrict__ yslot,
                                                 const float* __restrict__ g,
                                                 const float* __restrict__ bb,
                                                 float* __restrict__ bkt){
  int wid = threadIdx.x >> 6, lane = threadIdx.x & 63;
  long long row = (long long)blockIdx.x * 4 + wid;
  long long o = row * 256 + lane * 4;
  float sh = g_of(hslot[0]);
  float sy = g_of(yslot[0]);
  float4 hv = *(const float4*)(hraw + o);
  float4 yv = *(const float4*)(y + o);
  float t0 = fq_val(hv.x, sh) + fq_val(yv.x, sy);
  float t1 = fq_val(hv.y, sh) + fq_val(yv.y, sy);
  float t2 = fq_val(hv.z, sh) + fq_val(yv.z, sy);
  float t3 = fq_val(hv.w, sh) + fq_val(yv.w, sy);
  float sum = t0 + t1 + t2 + t3;
  for (int m = 32; m; m >>= 1) sum += __shfl_xor(sum, m);
  float mean = sum * (1.0f / 256.0f);
  float d0 = t0 - mean, d1 = t1 - mean, d2 = t2 - mean, d3 = t3 - mean;
  float vs = d0 * d0 + d1 * d1 + d2 * d2 + d3 * d3;
  for (int m = 32; m; m >>= 1) vs += __shfl_xor(vs, m);
  float r = rsqrtf(vs * (1.0f / 256.0f) + 1e-5f);
  float4 gv = *(const float4*)(g + lane * 4);
  float4 bv = *(const float4*)(bb + lane * 4);
  float4 ov;
  ov.x = d0 * r * gv.x + bv.x;
  ov.y = d1 * r * gv.y + bv.y;
  ov.z = d2 * r * gv.z + bv.z;
  ov.w = d3 * r * gv.w + bv.w;
  *(float4*)(y + o) = ov;
  float mx = fmaxf(fmaxf(fabsf(ov.x), fabsf(ov.y)), fmaxf(fabsf(ov.z), fabsf(ov.w)));
  bk_absmax(mx, bkt);
}

// ---- pooled = mean over L of fq(h) ---------------------------------------
__global__ __launch_bounds__(256) void mean_kernel(const float* __restrict__ h,
                                                   const float* __restrict__ slot,
                                                   float* __restrict__ pooled){
  int idx = blockIdx.x * 256 + threadIdx.x;   // 8192
  int d = idx & 255, b = idx >> 8;
  float s = g_of(slot[0]);
  const float* p = h + ((long long)b * 2048) * 256 + d;
  float a0 = 0, a1 = 0, a2 = 0, a3 = 0;
  for (int l = 0; l < 2048; l += 4){
    a0 += fq_val(p[(long long)l * 256], s);
    a1 += fq_val(p[(long long)(l + 1) * 256], s);
    a2 += fq_val(p[(long long)(l + 2) * 256], s);
    a3 += fq_val(p[(long long)(l + 3) * 256], s);
  }
  pooled[idx] = (a0 + a1 + a2 + a3) * (1.0f / 2048.0f);
}

// ---- classifier -----------------------------------------------------------
__global__ __launch_bounds__(320) void cls_kernel(const float* __restrict__ pooled,
                                                  const float* __restrict__ clsq,
                                                  const float* __restrict__ cb,
                                                  float* __restrict__ out){
  int tid = threadIdx.x;
  if (tid >= 320) return;
  int b = tid / 10, n = tid - b * 10;
  float acc = cb[n];
  const float* pr = pooled + b * 256;
  const float* wr = clsq + n * 256;
  for (int dd = 0; dd < 256; dd++) acc = fmaf(pr[dd], wr[dd], acc);
  out[tid] = acc;
}

// ===========================================================================
extern "C" void kernel_launch(void* const* d_in, const int* in_sizes, int n_in,
                              void* d_out, int out_size, void* d_ws, size_t ws_size,
                              hipStream_t stream) {
  const float* x_in   = (const float*)d_in[0];
  const float* pw_in  = (const float*)d_in[1];
  const float* pb_in  = (const float*)d_in[2];
  const float* pos_in = (const float*)d_in[3];
  const float* Win    = (const float*)d_in[4];
  const float* convw  = (const float*)d_in[5];
  const float* convb  = (const float*)d_in[6];
  const float* Wxp    = (const float*)d_in[7];
  const float* Wdt    = (const float*)d_in[8];
  const float* bdt    = (const float*)d_in[9];
  const float* Alog   = (const float*)d_in[10];
  const float* Dskip  = (const float*)d_in[11];
  const float* Wout   = (const float*)d_in[12];
  const float* lng    = (const float*)d_in[13];
  const float* lnb    = (const float*)d_in[14];
  const float* clsw   = (const float*)d_in[15];
  const float* clsb   = (const float*)d_in[16];
  float* out = (float*)d_out;

  // -------- workspace layout (floats) --------
  // slots: sc0=|x| sc1=|h0raw| sc2,3=h double-fq scales sc4=|pos| sc5,6=pos
  // scales sc7=|h_l0| sc8=|y0| sc9=|h_l1| sc10=|y1| sc11=|h_final|
  float* W = (float*)d_ws;
  float* sc     = W;                    // 64
  float* bkt    = W + 64;               // 8 × 1024 (64 buckets × stride 16)
  float* pwq    = W + 8256;             // 128
  float* clsq   = W + 8384;             // 2,560
  float* pooled = W + 10944;            // 8,192
  float* hbuf   = W + 19136;            // 16,777,216
  float* ybuf   = hbuf + 16777216;      // 16,777,216
  float* chunkW = ybuf + 16777216;

  const size_t fixed_f  = 33573568ULL;
  const size_t perseq_f = 1835008ULL;   // 2048*(512+256+32) + 3*65536
  int CB = 32;
  while (CB > 1 && (fixed_f + (size_t)CB * perseq_f) * 4 > ws_size) CB >>= 1;
  const long long R = (long long)CB * 2048;
  float* xz_c   = chunkW;
  float* xs_c   = xz_c + R * 512;
  float* proj_c = xs_c + R * 256;
  float* Pb_c   = proj_c + R * 32;
  float* Qb_c   = Pb_c + (long long)CB * 65536;
  float* Hs_c   = Qb_c + (long long)CB * 65536;

  hipMemsetAsync(sc, 0, (64 + 8 * 1024) * sizeof(float), stream);

  // scales for x and pos; patchify; addpos
  absmax_b<<<2048, 256, 0, stream>>>(x_in, 2097152LL, bkt + 0 * 1024);
  combine_kernel<<<1, 64, 0, stream>>>(bkt + 0 * 1024, sc + 0);
  fq_small<<<1, 256, 0, stream>>>(pw_in, pwq, 128);
  patchify_kernel<<<16384, 256, 0, stream>>>(x_in, pwq, pb_in, hbuf, sc + 0,
                                             bkt + 1 * 1024);
  combine_kernel<<<1, 64, 0, stream>>>(bkt + 1 * 1024, sc + 1);
  absmax_b<<<1024, 256, 0, stream>>>(pos_in, 524288LL, bkt + 2 * 1024);
  combine_kernel<<<1, 64, 0, stream>>>(bkt + 2 * 1024, sc + 4);
  chain_kernel<<<1, 64, 0, stream>>>(sc);
  addpos_kernel<<<16384, 256, 0, stream>>>(hbuf, pos_in, sc, bkt + 3 * 1024);
  combine_kernel<<<1, 64, 0, stream>>>(bkt + 3 * 1024, sc + 7);

  for (int i = 0; i < 2; i++){
    float* hin = (i == 0) ? hbuf : ybuf;
    float* yac = (i == 0) ? ybuf : hbuf;
    float* hs  = sc + (i == 0 ? 7 : 9);       // absmax of layer input
    float* ys  = sc + (i == 0 ? 8 : 10);      // absmax of y = yf+yb
    float* ybk = bkt + (i == 0 ? 4 : 6) * 1024;
    float* hbk = bkt + (i == 0 ? 5 : 7) * 1024;
    for (int dir = 0; dir < 2; dir++){
      int idx = i * 2 + dir;
      for (int b0 = 0; b0 < 32; b0 += CB){
        const float* hA = hin + (long long)b0 * 524288;
        float*       yC = yac + (long long)b0 * 524288;
        // xz = fq(u)(flip?) @ W_in   (R x 512)
        gemm64<<<dim3(8, R / 64), 256, 0, stream>>>(hA, Win + (long long)idx * 131072,
                                                    xz_c, 512, 256, dir, 0, 0,
                                                    hs, nullptr);
        conv_silu_kernel<<<R, 256, 0, stream>>>(xz_c, convw + idx * 1024,
                                                convb + idx * 256, xs_c);
        gemm_proj<<<R / 8, 256, 0, stream>>>(xs_c, Wxp + idx * 8192, proj_c);
        dt_kernel<<<R, 256, 0, stream>>>(proj_c, Wdt + idx * 4096, bdt + idx * 256, xz_c);
        scan1_kernel<<<CB * 256, 256, 0, stream>>>(xz_c, xs_c, proj_c,
                                                   Alog + idx * 2048, Pb_c, Qb_c);
        scan2_kernel<<<CB * 8, 256, 0, stream>>>(Pb_c, Qb_c, Hs_c);
        scan3_kernel<<<CB * 256, 256, 0, stream>>>(xz_c, xs_c, proj_c,
                                                   Alog + idx * 2048,
                                                   Dskip + idx * 256, Hs_c);
        // yac (+=flip) = xs @ W_out (R x 256); dir1 fuses absmax(yf+yb)
        gemm64<<<dim3(4, R / 64), 256, 0, stream>>>(xs_c, Wout + (long long)idx * 65536,
                                                    yC, 256, 256, 0, dir, dir,
                                                    nullptr, dir ? ybk : nullptr);
      }
    }
    combine_kernel<<<1, 64, 0, stream>>>(ybk, ys);
    // h_new(raw) = layernorm(fq(h) + fq(y)); absmax -> next slot
    ln_kernel<<<16384, 256, 0, stream>>>(hin, hs, yac, ys, lng + i * 256,
                                         lnb + i * 256, hbk);
    combine_kernel<<<1, 64, 0, stream>>>(hbk, sc + (i == 0 ? 9 : 11));
  }
  // final hidden raw in hbuf, scale sc11
  mean_kernel<<<32, 256, 0, stream>>>(hbuf, sc + 11, pooled);
  fq_small<<<1, 256, 0, stream>>>(pooled, pooled, 8192);
  fq_small<<<1, 256, 0, stream>>>(clsw, clsq, 2560);
  cls_kernel<<<1, 320, 0, stream>>>(pooled, clsq, clsb, out);
}

// Round 5
// 3541.619 us; speedup vs baseline: 4.0491x; 1.1745x over previous
//
#include <hip/hip_runtime.h>

// ---------------------------------------------------------------------------
// FEMBA full forward, f32. Shapes (fixed): B=32, L=2048, D=256, di=256, ds=8,
// dtr=16, K=4, nb=2, dirs=2, nc=10.
// Round 5: dt fused into scan1/scan3 (recomputed in-register from proj;
// dt_kernel and its 64MB/dir buffer traffic deleted), scan3 thread-owns-d
// (8 h-states in regs, no shfl), two-stage mean. GEMMs unchanged.
// ---------------------------------------------------------------------------

__device__ __forceinline__ float fq_val(float x, float s){
  float q = rintf(x / s);                 // round-half-even == jnp.round
  q = fminf(fmaxf(q, -128.0f), 127.0f);   // clip(-QMAX-1, QMAX)
  return q * s;
}

__device__ __forceinline__ float g_of(float a){ return fmaxf(a, 1e-8f) / 127.0f; }

// block absmax -> one atomic per block into spread bucket (blockDim==256)
__device__ __forceinline__ void bk_absmax(float v, float* bkt){
  for (int m = 32; m; m >>= 1) v = fmaxf(v, __shfl_xor(v, m));
  __shared__ float wmax[4];
  int lane = threadIdx.x & 63, wid = threadIdx.x >> 6;
  if (lane == 0) wmax[wid] = v;
  __syncthreads();
  if (threadIdx.x == 0){
    float m = fmaxf(fmaxf(wmax[0], wmax[1]), fmaxf(wmax[2], wmax[3]));
    atomicMax((unsigned int*)&bkt[(blockIdx.x & 63) * 16], __float_as_uint(m));
  }
}

// ---- grid absmax -> buckets ----------------------------------------------
__global__ __launch_bounds__(256) void absmax_b(const float* __restrict__ x,
                                                long long n, float* __restrict__ bkt){
  float m = 0.0f;
  for (long long i = (long long)blockIdx.x * 256 + threadIdx.x; i < n;
       i += (long long)gridDim.x * 256)
    m = fmaxf(m, fabsf(x[i]));
  bk_absmax(m, bkt);
}

// ---- fold 64 buckets -> one slot -----------------------------------------
__global__ __launch_bounds__(64) void combine_kernel(const float* __restrict__ bkt,
                                                     float* __restrict__ slot){
  float v = bkt[(threadIdx.x & 63) * 16];
  for (int m = 32; m; m >>= 1) v = fmaxf(v, __shfl_xor(v, m));
  if (threadIdx.x == 0) slot[0] = v;
}

// ---- scale chain for the double-fq of h and pos ---------------------------
__global__ __launch_bounds__(64) void chain_kernel(float* __restrict__ sc){
  if (threadIdx.x == 0){
    float s1 = g_of(sc[1]);
    float a1 = fq_val(sc[1], s1);
    sc[2] = s1; sc[3] = g_of(a1);
    float p1 = g_of(sc[4]);
    float a2 = fq_val(sc[4], p1);
    sc[5] = p1; sc[6] = g_of(a2);
  }
}

// ---- single-block fq for small tensors -----------------------------------
__global__ __launch_bounds__(256) void fq_small(const float* __restrict__ src,
                                                float* __restrict__ dst, int n){
  __shared__ float red[256];
  __shared__ float sS;
  float m = 0.0f;
  for (int i = threadIdx.x; i < n; i += 256) m = fmaxf(m, fabsf(src[i]));
  red[threadIdx.x] = m; __syncthreads();
  for (int s2 = 128; s2 > 0; s2 >>= 1){
    if (threadIdx.x < s2) red[threadIdx.x] = fmaxf(red[threadIdx.x], red[threadIdx.x + s2]);
    __syncthreads();
  }
  if (threadIdx.x == 0) sS = g_of(red[0]);
  __syncthreads();
  float s = sS;
  for (int i = threadIdx.x; i < n; i += 256) dst[i] = fq_val(src[i], s);
}

// ---- patchify (x4 vectorized) + inline fq(x) + bucketed absmax ------------
__global__ __launch_bounds__(256) void patchify_kernel(const float* __restrict__ x,
                                                       const float* __restrict__ pwq,
                                                       const float* __restrict__ pb,
                                                       float* __restrict__ h,
                                                       const float* __restrict__ slot,
                                                       float* __restrict__ bkt){
  int t = blockIdx.x * 256 + threadIdx.x;   // 4,194,304
  int q = t & 63;
  int l = (t >> 6) & 2047;
  int b = t >> 17;
  int d0 = q * 4;
  int c0 = d0 & 31, g = d0 >> 5;
  float s = g_of(slot[0]);
  const float* xp = x + ((long long)(b * 16 + 2 * g) * 4096 + 2 * l);
  float x0 = fq_val(xp[0], s),    x1 = fq_val(xp[1], s);
  float x2 = fq_val(xp[4096], s), x3 = fq_val(xp[4097], s);
  float4 o; float* op = (float*)&o;
  float mx = 0.0f;
#pragma unroll
  for (int j = 0; j < 4; j++){
    int c = c0 + j;
    float a = pb[c] + x0 * pwq[c * 4] + x1 * pwq[c * 4 + 1]
                    + x2 * pwq[c * 4 + 2] + x3 * pwq[c * 4 + 3];
    op[j] = a; mx = fmaxf(mx, fabsf(a));
  }
  *(float4*)(h + (long long)t * 4) = o;
  bk_absmax(mx, bkt);
}

// ---- h = fq(fq(h)) + fq(fq(pos)), raw sum; bucketed absmax ----------------
__global__ __launch_bounds__(256) void addpos_kernel(float* __restrict__ h,
                                                     const float* __restrict__ pos,
                                                     const float* __restrict__ sc,
                                                     float* __restrict__ bkt){
  long long t = (long long)blockIdx.x * 256 + threadIdx.x;  // 4,194,304
  float s1 = sc[2], s2 = sc[3], p1 = sc[5], p2 = sc[6];
  float4 hv = *(const float4*)(h + t * 4);
  float4 pv = *(const float4*)(pos + ((t * 4) & 524287));
  float* hp = (float*)&hv; float* pp = (float*)&pv;
  float4 o; float* op = (float*)&o;
  float mx = 0.0f;
#pragma unroll
  for (int j = 0; j < 4; j++){
    float v = fq_val(fq_val(hp[j], s1), s2) + fq_val(fq_val(pp[j], p1), p2);
    op[j] = v; mx = fmaxf(mx, fabsf(v));
  }
  *(float4*)(h + t * 4) = o;
  bk_absmax(mx, bkt);
}

// ---- tiled fp32 GEMM (unchanged from R4) ----------------------------------
__global__ __launch_bounds__(256) void gemm64(const float* __restrict__ A,
                                              const float* __restrict__ Bw,
                                              float* __restrict__ C,
                                              int N, int K,
                                              int flipA, int flipC, int accum,
                                              const float* __restrict__ aslot,
                                              float* __restrict__ bkt){
  __shared__ float As[32][68];
  __shared__ float Bs[32][64];
  int tid = threadIdx.x;
  int bn = blockIdx.x, bm = blockIdx.y;
  int tx = tid & 15, ty = tid >> 4;
  float sA = aslot ? g_of(aslot[0]) : 0.0f;

  int f0 = tid, f1 = tid + 256;
  int ar0 = f0 >> 3, ac0 = (f0 & 7) * 4;
  int ar1 = f1 >> 3, ac1 = (f1 & 7) * 4;
  int am0 = bm * 64 + ar0, am1 = bm * 64 + ar1;
  long long amr0 = flipA ? (((long long)(am0 >> 11)) << 11) + (2047 - (am0 & 2047)) : am0;
  long long amr1 = flipA ? (((long long)(am1 >> 11)) << 11) + (2047 - (am1 & 2047)) : am1;
  const float* Ap0 = A + amr0 * (long long)K + ac0;
  const float* Ap1 = A + amr1 * (long long)K + ac1;
  int br0 = f0 >> 4, bc0 = (f0 & 15) * 4;
  int br1 = f1 >> 4, bc1 = (f1 & 15) * 4;
  const float* Bp0 = Bw + (long long)br0 * N + bn * 64 + bc0;
  const float* Bp1 = Bw + (long long)br1 * N + bn * 64 + bc1;

  float acc[4][4] = {};
  for (int k0 = 0; k0 < K; k0 += 32){
    float4 a0v = *(const float4*)(Ap0 + k0);
    float4 a1v = *(const float4*)(Ap1 + k0);
    float4 b0v = *(const float4*)(Bp0 + (long long)k0 * N);
    float4 b1v = *(const float4*)(Bp1 + (long long)k0 * N);
    if (aslot){
      a0v.x = fq_val(a0v.x, sA); a0v.y = fq_val(a0v.y, sA);
      a0v.z = fq_val(a0v.z, sA); a0v.w = fq_val(a0v.w, sA);
      a1v.x = fq_val(a1v.x, sA); a1v.y = fq_val(a1v.y, sA);
      a1v.z = fq_val(a1v.z, sA); a1v.w = fq_val(a1v.w, sA);
    }
    As[ac0 + 0][ar0] = a0v.x; As[ac0 + 1][ar0] = a0v.y;
    As[ac0 + 2][ar0] = a0v.z; As[ac0 + 3][ar0] = a0v.w;
    As[ac1 + 0][ar1] = a1v.x; As[ac1 + 1][ar1] = a1v.y;
    As[ac1 + 2][ar1] = a1v.z; As[ac1 + 3][ar1] = a1v.w;
    *(float4*)&Bs[br0][bc0] = b0v;
    *(float4*)&Bs[br1][bc1] = b1v;
    __syncthreads();
#pragma unroll
    for (int kk = 0; kk < 32; kk++){
      float4 av = *(const float4*)&As[kk][ty * 4];
      float4 bv = *(const float4*)&Bs[kk][tx * 4];
      float ar[4] = {av.x, av.y, av.z, av.w};
      float br[4] = {bv.x, bv.y, bv.z, bv.w};
#pragma unroll
      for (int i = 0; i < 4; i++)
#pragma unroll
        for (int j = 0; j < 4; j++)
          acc[i][j] = fmaf(ar[i], br[j], acc[i][j]);
    }
    __syncthreads();
  }
  float mx = 0.0f;
#pragma unroll
  for (int i = 0; i < 4; i++){
    int m = bm * 64 + ty * 4 + i;
    long long mr = flipC ? (((long long)(m >> 11)) << 11) + (2047 - (m & 2047)) : m;
    float* Cp = C + mr * (long long)N + bn * 64 + tx * 4;
    if (accum){
#pragma unroll
      for (int j = 0; j < 4; j++){
        float v = Cp[j] + acc[i][j];
        Cp[j] = v;
        mx = fmaxf(mx, fabsf(v));
      }
    } else {
      float4 v = make_float4(acc[i][0], acc[i][1], acc[i][2], acc[i][3]);
      *(float4*)Cp = v;
    }
  }
  if (bkt) bk_absmax(mx, bkt);
}

// ---- depthwise causal conv (K=4) + SiLU ----------------------------------
__global__ __launch_bounds__(256) void conv_silu_kernel(const float* __restrict__ xz,
                                                        const float* __restrict__ cw,
                                                        const float* __restrict__ cb,
                                                        float* __restrict__ xs){
  long long idx = (long long)blockIdx.x * 256 + threadIdx.x;
  int d = (int)(idx & 255);
  long long bl = idx >> 8;
  int l = (int)(bl & 2047);
  const float* base = xz + (bl << 9) + d;   // row stride 512
  float w0 = cw[d*4], w1 = cw[d*4+1], w2 = cw[d*4+2], w3 = cw[d*4+3];
  float acc = cb[d] + w3 * base[0];
  if (l >= 1) acc += w2 * base[-512];
  if (l >= 2) acc += w1 * base[-1024];
  if (l >= 3) acc += w0 * base[-1536];
  xs[idx] = acc / (1.0f + expf(-acc));      // silu
}

// ---- proj = xs @ W_xp (K=256, N=32); 8 rows per block ---------------------
__global__ __launch_bounds__(256) void gemm_proj(const float* __restrict__ xs,
                                                 const float* __restrict__ W,
                                                 float* __restrict__ proj){
  __shared__ float As[2048];
  long long row0 = (long long)blockIdx.x * 8;
  for (int i = threadIdx.x; i < 2048; i += 256) As[i] = xs[row0 * 256 + i];
  __syncthreads();
  int r = threadIdx.x >> 5, cidx = threadIdx.x & 31;
  float acc = 0.0f;
#pragma unroll 8
  for (int k = 0; k < 256; k++) acc = fmaf(As[r * 256 + k], W[k * 32 + cidx], acc);
  proj[(row0 + r) * 32 + cidx] = acc;
}

// ===== segment-parallel selective scan, dt fused (recomputed in-register) ==
// block = (b, seg); thread t owns channel d = t.
__global__ __launch_bounds__(256) void scan1_kernel(const float* __restrict__ xs,
                                                    const float* __restrict__ proj,
                                                    const float* __restrict__ Wdt,
                                                    const float* __restrict__ bdt,
                                                    const float* __restrict__ A_log,
                                                    float* __restrict__ Pb,
                                                    float* __restrict__ Qb){
  __shared__ float pj[64][32];
  int blk = blockIdx.x;
  int seg = blk & 31, b = blk >> 5;
  int d = threadIdx.x;
  long long rowbase = (long long)b * 2048 + seg * 64;
  {
    const float4* src4 = (const float4*)(proj + rowbase * 32);
    float4* dst4 = (float4*)&pj[0][0];
    for (int i = threadIdx.x; i < 512; i += 256) dst4[i] = src4[i];
  }
  __syncthreads();
  float wdt[16];
#pragma unroll
  for (int r = 0; r < 16; r++) wdt[r] = Wdt[r * 256 + d];
  float bd = bdt[d];
  float A[8];
#pragma unroll
  for (int s = 0; s < 8; s++) A[s] = -expf(A_log[d * 8 + s]);
  const float* xp = xs + rowbase * 256 + d;
  float P[8], q[8];
#pragma unroll
  for (int s = 0; s < 8; s++){ P[s] = 1.0f; q[s] = 0.0f; }
  for (int l = 0; l < 64; l++){
    float acc = bd;
#pragma unroll
    for (int r = 0; r < 16; r++) acc = fmaf(pj[l][r], wdt[r], acc);
    float dt = (acc > 0.0f) ? acc + log1pf(expf(-acc)) : log1pf(expf(acc));
    float x = xp[(long long)l * 256];
    float dx = dt * x;
#pragma unroll
    for (int s = 0; s < 8; s++){
      float dA = expf(dt * A[s]);
      P[s] *= dA;
      q[s] = fmaf(dA, q[s], dx * pj[l][16 + s]);
    }
  }
  long long obase = ((long long)blk << 11) + (long long)d * 8;
  *(float4*)(Pb + obase)     = make_float4(P[0], P[1], P[2], P[3]);
  *(float4*)(Pb + obase + 4) = make_float4(P[4], P[5], P[6], P[7]);
  *(float4*)(Qb + obase)     = make_float4(q[0], q[1], q[2], q[3]);
  *(float4*)(Qb + obase + 4) = make_float4(q[4], q[5], q[6], q[7]);
}

// scan2: serial prefix over 32 segments per (b, d*8+s)
__global__ __launch_bounds__(256) void scan2_kernel(const float* __restrict__ Pb,
                                                    const float* __restrict__ Qb,
                                                    float* __restrict__ Hs){
  int t = blockIdx.x * 256 + threadIdx.x;  // CB*2048
  int ds_ = t & 2047;
  int b = t >> 11;
  float h = 0.0f;
#pragma unroll
  for (int g = 0; g < 32; g++){
    long long idx = (((long long)b * 32 + g) << 11) + ds_;
    Hs[idx] = h;
    h = fmaf(Pb[idx], h, Qb[idx]);
  }
}

// scan3: thread owns d; 8 h-states in regs; dt recomputed; gated y -> xs ----
__global__ __launch_bounds__(256) void scan3_kernel(const float* __restrict__ xz,
                                                    float* __restrict__ xs,
                                                    const float* __restrict__ proj,
                                                    const float* __restrict__ Wdt,
                                                    const float* __restrict__ bdt,
                                                    const float* __restrict__ A_log,
                                                    const float* __restrict__ Dsk,
                                                    const float* __restrict__ Hs){
  __shared__ float pj[64][32];
  int blk = blockIdx.x;
  int seg = blk & 31, b = blk >> 5;
  int d = threadIdx.x;
  long long rowbase = (long long)b * 2048 + seg * 64;
  {
    const float4* src4 = (const float4*)(proj + rowbase * 32);
    float4* dst4 = (float4*)&pj[0][0];
    for (int i = threadIdx.x; i < 512; i += 256) dst4[i] = src4[i];
  }
  __syncthreads();
  float wdt[16];
#pragma unroll
  for (int r = 0; r < 16; r++) wdt[r] = Wdt[r * 256 + d];
  float bd = bdt[d];
  float A[8];
#pragma unroll
  for (int s = 0; s < 8; s++) A[s] = -expf(A_log[d * 8 + s]);
  float Dv = Dsk[d];
  long long hbase = ((long long)blk << 11) + (long long)d * 8;
  float4 h0 = *(const float4*)(Hs + hbase);
  float4 h1 = *(const float4*)(Hs + hbase + 4);
  float h[8] = {h0.x, h0.y, h0.z, h0.w, h1.x, h1.y, h1.z, h1.w};
  float* xp = xs + rowbase * 256 + d;
  const float* zp = xz + rowbase * 512 + 256 + d;
  for (int l = 0; l < 64; l++){
    float acc = bd;
#pragma unroll
    for (int r = 0; r < 16; r++) acc = fmaf(pj[l][r], wdt[r], acc);
    float dt = (acc > 0.0f) ? acc + log1pf(expf(-acc)) : log1pf(expf(acc));
    float x = xp[(long long)l * 256];
    float dx = dt * x;
    float y = 0.0f;
#pragma unroll
    for (int s = 0; s < 8; s++){
      float dA = expf(dt * A[s]);
      h[s] = fmaf(dA, h[s], dx * pj[l][16 + s]);
      y = fmaf(h[s], pj[l][24 + s], y);
    }
    y = fmaf(x, Dv, y);
    float z = zp[(long long)l * 512];
    xp[(long long)l * 256] = y * (z / (1.0f + expf(-z)));
  }
}

// ---- layernorm(fq(hres) + fq(y)) : one row per wave ------------------------
__global__ __launch_bounds__(256) void ln_kernel(const float* __restrict__ hraw,
                                                 const float* __restrict__ hslot,
                                                 float* __restrict__ y,
                                                 const float* __restrict__ yslot,
                                                 const float* __restrict__ g,
                                                 const float* __restrict__ bb,
                                                 float* __restrict__ bkt){
  int wid = threadIdx.x >> 6, lane = threadIdx.x & 63;
  long long row = (long long)blockIdx.x * 4 + wid;
  long long o = row * 256 + lane * 4;
  float sh = g_of(hslot[0]);
  float sy = g_of(yslot[0]);
  float4 hv = *(const float4*)(hraw + o);
  float4 yv = *(const float4*)(y + o);
  float t0 = fq_val(hv.x, sh) + fq_val(yv.x, sy);
  float t1 = fq_val(hv.y, sh) + fq_val(yv.y, sy);
  float t2 = fq_val(hv.z, sh) + fq_val(yv.z, sy);
  float t3 = fq_val(hv.w, sh) + fq_val(yv.w, sy);
  float sum = t0 + t1 + t2 + t3;
  for (int m = 32; m; m >>= 1) sum += __shfl_xor(sum, m);
  float mean = sum * (1.0f / 256.0f);
  float d0 = t0 - mean, d1 = t1 - mean, d2 = t2 - mean, d3 = t3 - mean;
  float vs = d0 * d0 + d1 * d1 + d2 * d2 + d3 * d3;
  for (int m = 32; m; m >>= 1) vs += __shfl_xor(vs, m);
  float r = rsqrtf(vs * (1.0f / 256.0f) + 1e-5f);
  float4 gv = *(const float4*)(g + lane * 4);
  float4 bv = *(const float4*)(bb + lane * 4);
  float4 ov;
  ov.x = d0 * r * gv.x + bv.x;
  ov.y = d1 * r * gv.y + bv.y;
  ov.z = d2 * r * gv.z + bv.z;
  ov.w = d3 * r * gv.w + bv.w;
  *(float4*)(y + o) = ov;
  float mx = fmaxf(fmaxf(fabsf(ov.x), fabsf(ov.y)), fmaxf(fabsf(ov.z), fabsf(ov.w)));
  bk_absmax(mx, bkt);
}

// ---- two-stage mean of fq(h) over L ---------------------------------------
__global__ __launch_bounds__(256) void mean_part(const float* __restrict__ h,
                                                 const float* __restrict__ slot,
                                                 float* __restrict__ part){
  int blk = blockIdx.x;          // 2048: b*64 + lc
  int d = threadIdx.x;
  int lc = blk & 63, b = blk >> 6;
  float s = g_of(slot[0]);
  const float* p = h + ((long long)b * 2048 + lc * 32) * 256 + d;
  float a = 0.0f;
  for (int l = 0; l < 32; l++) a += fq_val(p[(long long)l * 256], s);
  part[(long long)blk * 256 + d] = a;
}

__global__ __launch_bounds__(256) void mean_fin(const float* __restrict__ part,
                                                float* __restrict__ pooled){
  int idx = blockIdx.x * 256 + threadIdx.x;   // 8192
  int d = idx & 255, b = idx >> 8;
  float a = 0.0f;
  for (int lc = 0; lc < 64; lc++)
    a += part[((long long)b * 64 + lc) * 256 + d];
  pooled[idx] = a * (1.0f / 2048.0f);
}

// ---- classifier -----------------------------------------------------------
__global__ __launch_bounds__(320) void cls_kernel(const float* __restrict__ pooled,
                                                  const float* __restrict__ clsq,
                                                  const float* __restrict__ cb,
                                                  float* __restrict__ out){
  int tid = threadIdx.x;
  if (tid >= 320) return;
  int b = tid / 10, n = tid - b * 10;
  float acc = cb[n];
  const float* pr = pooled + b * 256;
  const float* wr = clsq + n * 256;
  for (int dd = 0; dd < 256; dd++) acc = fmaf(pr[dd], wr[dd], acc);
  out[tid] = acc;
}

// ===========================================================================
extern "C" void kernel_launch(void* const* d_in, const int* in_sizes, int n_in,
                              void* d_out, int out_size, void* d_ws, size_t ws_size,
                              hipStream_t stream) {
  const float* x_in   = (const float*)d_in[0];
  const float* pw_in  = (const float*)d_in[1];
  const float* pb_in  = (const float*)d_in[2];
  const float* pos_in = (const float*)d_in[3];
  const float* Win    = (const float*)d_in[4];
  const float* convw  = (const float*)d_in[5];
  const float* convb  = (const float*)d_in[6];
  const float* Wxp    = (const float*)d_in[7];
  const float* Wdt    = (const float*)d_in[8];
  const float* bdt    = (const float*)d_in[9];
  const float* Alog   = (const float*)d_in[10];
  const float* Dskip  = (const float*)d_in[11];
  const float* Wout   = (const float*)d_in[12];
  const float* lng    = (const float*)d_in[13];
  const float* lnb    = (const float*)d_in[14];
  const float* clsw   = (const float*)d_in[15];
  const float* clsb   = (const float*)d_in[16];
  float* out = (float*)d_out;

  // -------- workspace layout (floats) --------
  float* W = (float*)d_ws;
  float* sc     = W;                    // 64
  float* bkt    = W + 64;               // 8 × 1024
  float* pwq    = W + 8256;             // 128
  float* clsq   = W + 8384;             // 2,560
  float* pooled = W + 10944;            // 8,192
  float* mpart  = W + 19136;            // 524,288
  float* hbuf   = W + 543424;           // 16,777,216
  float* ybuf   = hbuf + 16777216;      // 16,777,216
  float* chunkW = ybuf + 16777216;

  const size_t fixed_f  = 34097856ULL;
  const size_t perseq_f = 1835008ULL;   // 2048*(512+256+32) + 3*65536
  int CB = 32;
  while (CB > 1 && (fixed_f + (size_t)CB * perseq_f) * 4 > ws_size) CB >>= 1;
  const long long R = (long long)CB * 2048;
  float* xz_c   = chunkW;
  float* xs_c   = xz_c + R * 512;
  float* proj_c = xs_c + R * 256;
  float* Pb_c   = proj_c + R * 32;
  float* Qb_c   = Pb_c + (long long)CB * 65536;
  float* Hs_c   = Qb_c + (long long)CB * 65536;

  hipMemsetAsync(sc, 0, (64 + 8 * 1024) * sizeof(float), stream);

  absmax_b<<<2048, 256, 0, stream>>>(x_in, 2097152LL, bkt + 0 * 1024);
  combine_kernel<<<1, 64, 0, stream>>>(bkt + 0 * 1024, sc + 0);
  fq_small<<<1, 256, 0, stream>>>(pw_in, pwq, 128);
  patchify_kernel<<<16384, 256, 0, stream>>>(x_in, pwq, pb_in, hbuf, sc + 0,
                                             bkt + 1 * 1024);
  combine_kernel<<<1, 64, 0, stream>>>(bkt + 1 * 1024, sc + 1);
  absmax_b<<<1024, 256, 0, stream>>>(pos_in, 524288LL, bkt + 2 * 1024);
  combine_kernel<<<1, 64, 0, stream>>>(bkt + 2 * 1024, sc + 4);
  chain_kernel<<<1, 64, 0, stream>>>(sc);
  addpos_kernel<<<16384, 256, 0, stream>>>(hbuf, pos_in, sc, bkt + 3 * 1024);
  combine_kernel<<<1, 64, 0, stream>>>(bkt + 3 * 1024, sc + 7);

  for (int i = 0; i < 2; i++){
    float* hin = (i == 0) ? hbuf : ybuf;
    float* yac = (i == 0) ? ybuf : hbuf;
    float* hs  = sc + (i == 0 ? 7 : 9);
    float* ys  = sc + (i == 0 ? 8 : 10);
    float* ybk = bkt + (i == 0 ? 4 : 6) * 1024;
    float* hbk = bkt + (i == 0 ? 5 : 7) * 1024;
    for (int dir = 0; dir < 2; dir++){
      int idx = i * 2 + dir;
      for (int b0 = 0; b0 < 32; b0 += CB){
        const float* hA = hin + (long long)b0 * 524288;
        float*       yC = yac + (long long)b0 * 524288;
        // xz = fq(u)(flip?) @ W_in   (R x 512)
        gemm64<<<dim3(8, R / 64), 256, 0, stream>>>(hA, Win + (long long)idx * 131072,
                                                    xz_c, 512, 256, dir, 0, 0,
                                                    hs, nullptr);
        conv_silu_kernel<<<R, 256, 0, stream>>>(xz_c, convw + idx * 1024,
                                                convb + idx * 256, xs_c);
        gemm_proj<<<R / 8, 256, 0, stream>>>(xs_c, Wxp + idx * 8192, proj_c);
        // scans (dt recomputed in-register from proj)
        scan1_kernel<<<CB * 32, 256, 0, stream>>>(xs_c, proj_c,
                                                  Wdt + idx * 4096, bdt + idx * 256,
                                                  Alog + idx * 2048, Pb_c, Qb_c);
        scan2_kernel<<<CB * 8, 256, 0, stream>>>(Pb_c, Qb_c, Hs_c);
        scan3_kernel<<<CB * 32, 256, 0, stream>>>(xz_c, xs_c, proj_c,
                                                  Wdt + idx * 4096, bdt + idx * 256,
                                                  Alog + idx * 2048,
                                                  Dskip + idx * 256, Hs_c);
        // yac (+=flip) = xs @ W_out (R x 256); dir1 fuses absmax(yf+yb)
        gemm64<<<dim3(4, R / 64), 256, 0, stream>>>(xs_c, Wout + (long long)idx * 65536,
                                                    yC, 256, 256, 0, dir, dir,
                                                    nullptr, dir ? ybk : nullptr);
      }
    }
    combine_kernel<<<1, 64, 0, stream>>>(ybk, ys);
    ln_kernel<<<16384, 256, 0, stream>>>(hin, hs, yac, ys, lng + i * 256,
                                         lnb + i * 256, hbk);
    combine_kernel<<<1, 64, 0, stream>>>(hbk, sc + (i == 0 ? 9 : 11));
  }
  // final hidden raw in hbuf, scale sc11
  mean_part<<<2048, 256, 0, stream>>>(hbuf, sc + 11, mpart);
  mean_fin<<<32, 256, 0, stream>>>(mpart, pooled);
  fq_small<<<1, 256, 0, stream>>>(pooled, pooled, 8192);
  fq_small<<<1, 256, 0, stream>>>(clsw, clsq, 2560);
  cls_kernel<<<1, 320, 0, stream>>>(pooled, clsq, clsb, out);
}

// Round 6
// 2858.750 us; speedup vs baseline: 5.0163x; 1.2389x over previous
//
#include <hip/hip_runtime.h>

// ---------------------------------------------------------------------------
// FEMBA full forward. Shapes fixed: B=32, L=2048, D=256, di=256, ds=8, dtr=16,
// K=4, nb=2, dirs=2, nc=10.
// Round 6: big GEMMs on MFMA (bf16). W_in: A=fq(u)=s*Q with Q int8 exact in
// bf16 -> 2 products vs split weights (hi+lo). W_out: 3-product bf16 split.
// Weights split+transposed once per call (wsplit). Everything else = R5.
// ---------------------------------------------------------------------------

typedef __attribute__((ext_vector_type(8))) short bfrag;   // 8 bf16
typedef __attribute__((ext_vector_type(4))) float cfrag;   // 4 f32 acc

__device__ __forceinline__ float fq_val(float x, float s){
  float q = rintf(x / s);
  q = fminf(fmaxf(q, -128.0f), 127.0f);
  return q * s;
}
__device__ __forceinline__ float g_of(float a){ return fmaxf(a, 1e-8f) / 127.0f; }

__device__ __forceinline__ short f2bf(float f){           // RNE f32->bf16 bits
  unsigned u = __float_as_uint(f);
  u += 0x7fff + ((u >> 16) & 1);
  return (short)(u >> 16);
}
__device__ __forceinline__ float bf2f(short h){
  return __uint_as_float(((unsigned)(unsigned short)h) << 16);
}

// block absmax -> one atomic per block into spread bucket (blockDim==256)
__device__ __forceinline__ void bk_absmax(float v, float* bkt){
  for (int m = 32; m; m >>= 1) v = fmaxf(v, __shfl_xor(v, m));
  __shared__ float wmax[4];
  int lane = threadIdx.x & 63, wid = threadIdx.x >> 6;
  if (lane == 0) wmax[wid] = v;
  __syncthreads();
  if (threadIdx.x == 0){
    float m = fmaxf(fmaxf(wmax[0], wmax[1]), fmaxf(wmax[2], wmax[3]));
    atomicMax((unsigned int*)&bkt[(blockIdx.x & 63) * 16], __float_as_uint(m));
  }
}

__global__ __launch_bounds__(256) void absmax_b(const float* __restrict__ x,
                                                long long n, float* __restrict__ bkt){
  float m = 0.0f;
  for (long long i = (long long)blockIdx.x * 256 + threadIdx.x; i < n;
       i += (long long)gridDim.x * 256)
    m = fmaxf(m, fabsf(x[i]));
  bk_absmax(m, bkt);
}

__global__ __launch_bounds__(64) void combine_kernel(const float* __restrict__ bkt,
                                                     float* __restrict__ slot){
  float v = bkt[(threadIdx.x & 63) * 16];
  for (int m = 32; m; m >>= 1) v = fmaxf(v, __shfl_xor(v, m));
  if (threadIdx.x == 0) slot[0] = v;
}

__global__ __launch_bounds__(64) void chain_kernel(float* __restrict__ sc){
  if (threadIdx.x == 0){
    float s1 = g_of(sc[1]);
    float a1 = fq_val(sc[1], s1);
    sc[2] = s1; sc[3] = g_of(a1);
    float p1 = g_of(sc[4]);
    float a2 = fq_val(sc[4], p1);
    sc[5] = p1; sc[6] = g_of(a2);
  }
}

__global__ __launch_bounds__(256) void fq_small(const float* __restrict__ src,
                                                float* __restrict__ dst, int n){
  __shared__ float red[256];
  __shared__ float sS;
  float m = 0.0f;
  for (int i = threadIdx.x; i < n; i += 256) m = fmaxf(m, fabsf(src[i]));
  red[threadIdx.x] = m; __syncthreads();
  for (int s2 = 128; s2 > 0; s2 >>= 1){
    if (threadIdx.x < s2) red[threadIdx.x] = fmaxf(red[threadIdx.x], red[threadIdx.x + s2]);
    __syncthreads();
  }
  if (threadIdx.x == 0) sS = g_of(red[0]);
  __syncthreads();
  float s = sS;
  for (int i = threadIdx.x; i < n; i += 256) dst[i] = fq_val(src[i], s);
}

// ---- weight split+transpose: W[k][n] f32 -> WhT[n][k], WlT[n][k] bf16 -----
__global__ __launch_bounds__(256) void wsplit(const float* __restrict__ src,
                                              short* __restrict__ dh,
                                              short* __restrict__ dl, int N){
  __shared__ float tile[64][65];
  int n0 = blockIdx.x * 64, k0 = blockIdx.y * 64, id = blockIdx.z;
  const float* S = src + (long long)id * 256 * N;
  short* H = dh + (long long)id * N * 256;
  short* L = dl + (long long)id * N * 256;
  int t = threadIdx.x;
#pragma unroll
  for (int i = 0; i < 16; i++){
    int idx = i * 256 + t;
    int kr = idx >> 6, nc = idx & 63;
    tile[kr][nc] = S[(long long)(k0 + kr) * N + n0 + nc];
  }
  __syncthreads();
#pragma unroll
  for (int i = 0; i < 16; i++){
    int idx = i * 256 + t;
    int nr = idx >> 6, kc = idx & 63;
    float f = tile[kc][nr];
    short h = f2bf(f);
    short l = f2bf(f - bf2f(h));
    H[(long long)(n0 + nr) * 256 + k0 + kc] = h;
    L[(long long)(n0 + nr) * 256 + k0 + kc] = l;
  }
}

// ---- patchify (x4 vectorized) + inline fq(x) + bucketed absmax ------------
__global__ __launch_bounds__(256) void patchify_kernel(const float* __restrict__ x,
                                                       const float* __restrict__ pwq,
                                                       const float* __restrict__ pb,
                                                       float* __restrict__ h,
                                                       const float* __restrict__ slot,
                                                       float* __restrict__ bkt){
  int t = blockIdx.x * 256 + threadIdx.x;
  int q = t & 63;
  int l = (t >> 6) & 2047;
  int b = t >> 17;
  int d0 = q * 4;
  int c0 = d0 & 31, g = d0 >> 5;
  float s = g_of(slot[0]);
  const float* xp = x + ((long long)(b * 16 + 2 * g) * 4096 + 2 * l);
  float x0 = fq_val(xp[0], s),    x1 = fq_val(xp[1], s);
  float x2 = fq_val(xp[4096], s), x3 = fq_val(xp[4097], s);
  float4 o; float* op = (float*)&o;
  float mx = 0.0f;
#pragma unroll
  for (int j = 0; j < 4; j++){
    int c = c0 + j;
    float a = pb[c] + x0 * pwq[c * 4] + x1 * pwq[c * 4 + 1]
                    + x2 * pwq[c * 4 + 2] + x3 * pwq[c * 4 + 3];
    op[j] = a; mx = fmaxf(mx, fabsf(a));
  }
  *(float4*)(h + (long long)t * 4) = o;
  bk_absmax(mx, bkt);
}

__global__ __launch_bounds__(256) void addpos_kernel(float* __restrict__ h,
                                                     const float* __restrict__ pos,
                                                     const float* __restrict__ sc,
                                                     float* __restrict__ bkt){
  long long t = (long long)blockIdx.x * 256 + threadIdx.x;
  float s1 = sc[2], s2 = sc[3], p1 = sc[5], p2 = sc[6];
  float4 hv = *(const float4*)(h + t * 4);
  float4 pv = *(const float4*)(pos + ((t * 4) & 524287));
  float* hp = (float*)&hv; float* pp = (float*)&pv;
  float4 o; float* op = (float*)&o;
  float mx = 0.0f;
#pragma unroll
  for (int j = 0; j < 4; j++){
    float v = fq_val(fq_val(hp[j], s1), s2) + fq_val(fq_val(pp[j], p1), p2);
    op[j] = v; mx = fmaxf(mx, fabsf(v));
  }
  *(float4*)(h + t * 4) = o;
  bk_absmax(mx, bkt);
}

// ---- MFMA GEMM: C(R,N) = A(R,256) @ B(256,N) via bf16 products ------------
// qmode=1: A is fq'd on read -> integer Q (exact bf16); C = sA*(Q@Bh + Q@Bl).
// qmode=0: A split hi/lo; C = ah@bh + al@bh + ah@bl.
// Block tile 128x128, 4 waves (2x2), wave tile 64x64 = 4x4 mfma 16x16x32.
__global__ __launch_bounds__(256) void gemm_mfma(const float* __restrict__ A,
                                                 const short* __restrict__ BhT,
                                                 const short* __restrict__ BlT,
                                                 float* __restrict__ C,
                                                 int N, int flipA, int flipC,
                                                 int accum, int qmode,
                                                 const float* __restrict__ aslot,
                                                 float* __restrict__ bkt){
  __shared__ short Ah[128][40];
  __shared__ short Al[128][40];
  __shared__ short Bh[128][40];
  __shared__ short Bl[128][40];
  int t = threadIdx.x;
  int bn = blockIdx.x, bm = blockIdx.y;
  int lane = t & 63, wv = t >> 6;
  int wm = wv & 1, wn = wv >> 1;
  int qd = lane >> 4, l16 = lane & 15;
  float sA = qmode ? g_of(aslot[0]) : 0.0f;

  cfrag acc[4][4];
#pragma unroll
  for (int i = 0; i < 4; i++)
#pragma unroll
    for (int j = 0; j < 4; j++)
      acc[i][j] = (cfrag){0.f, 0.f, 0.f, 0.f};

  for (int k0 = 0; k0 < 256; k0 += 32){
    // stage A: 128 rows x 32 cols f32 -> bf16 (Q or hi/lo)
#pragma unroll
    for (int i = 0; i < 4; i++){
      int idx = i * 256 + t;
      int row = idx >> 3, c4 = (idx & 7) * 4;
      int mg = bm * 128 + row;
      long long mr = flipA ? (((long long)(mg >> 11)) << 11) + (2047 - (mg & 2047)) : mg;
      float4 v = *(const float4*)(A + mr * 256 + k0 + c4);
      float* vp = (float*)&v;
      if (qmode){
#pragma unroll
        for (int j = 0; j < 4; j++){
          float qv = fminf(fmaxf(rintf(vp[j] / sA), -128.0f), 127.0f);
          Ah[row][c4 + j] = f2bf(qv);
        }
      } else {
#pragma unroll
        for (int j = 0; j < 4; j++){
          short h = f2bf(vp[j]);
          Ah[row][c4 + j] = h;
          Al[row][c4 + j] = f2bf(vp[j] - bf2f(h));
        }
      }
    }
    // stage B^T: 128 n-rows x 32 k-cols bf16 (hi and lo)
#pragma unroll
    for (int i = 0; i < 2; i++){
      int idx = i * 256 + t;
      int row = idx >> 2, c8 = (idx & 3) * 8;
      long long go = (long long)(bn * 128 + row) * 256 + k0 + c8;
      *(bfrag*)&Bh[row][c8] = *(const bfrag*)(BhT + go);
      *(bfrag*)&Bl[row][c8] = *(const bfrag*)(BlT + go);
    }
    __syncthreads();

    bfrag bh[4], bl[4];
#pragma unroll
    for (int ni = 0; ni < 4; ni++){
      bh[ni] = *(const bfrag*)&Bh[wn * 64 + ni * 16 + l16][qd * 8];
      bl[ni] = *(const bfrag*)&Bl[wn * 64 + ni * 16 + l16][qd * 8];
    }
#pragma unroll
    for (int mi = 0; mi < 4; mi++){
      bfrag ah = *(const bfrag*)&Ah[wm * 64 + mi * 16 + l16][qd * 8];
      if (qmode){
#pragma unroll
        for (int ni = 0; ni < 4; ni++){
          acc[mi][ni] = __builtin_amdgcn_mfma_f32_16x16x32_bf16(ah, bh[ni], acc[mi][ni], 0, 0, 0);
          acc[mi][ni] = __builtin_amdgcn_mfma_f32_16x16x32_bf16(ah, bl[ni], acc[mi][ni], 0, 0, 0);
        }
      } else {
        bfrag al = *(const bfrag*)&Al[wm * 64 + mi * 16 + l16][qd * 8];
#pragma unroll
        for (int ni = 0; ni < 4; ni++){
          acc[mi][ni] = __builtin_amdgcn_mfma_f32_16x16x32_bf16(ah, bh[ni], acc[mi][ni], 0, 0, 0);
          acc[mi][ni] = __builtin_amdgcn_mfma_f32_16x16x32_bf16(al, bh[ni], acc[mi][ni], 0, 0, 0);
          acc[mi][ni] = __builtin_amdgcn_mfma_f32_16x16x32_bf16(ah, bl[ni], acc[mi][ni], 0, 0, 0);
        }
      }
    }
    __syncthreads();
  }

  // epilogue: D[row][col]: col = l16 (+ tiles), row = qd*4 + r (+ tiles)
  float mx = 0.0f;
#pragma unroll
  for (int mi = 0; mi < 4; mi++){
#pragma unroll
    for (int ni = 0; ni < 4; ni++){
      int colg = bn * 128 + wn * 64 + ni * 16 + l16;
#pragma unroll
      for (int r = 0; r < 4; r++){
        int mg = bm * 128 + wm * 64 + mi * 16 + qd * 4 + r;
        long long mr = flipC ? (((long long)(mg >> 11)) << 11) + (2047 - (mg & 2047)) : mg;
        float v = acc[mi][ni][r];
        if (qmode) v *= sA;
        float* Cp = C + mr * (long long)N + colg;
        if (accum){
          float nv = *Cp + v;
          *Cp = nv;
          mx = fmaxf(mx, fabsf(nv));
        } else {
          *Cp = v;
        }
      }
    }
  }
  if (bkt) bk_absmax(mx, bkt);
}

// ---- depthwise causal conv (K=4) + SiLU ----------------------------------
__global__ __launch_bounds__(256) void conv_silu_kernel(const float* __restrict__ xz,
                                                        const float* __restrict__ cw,
                                                        const float* __restrict__ cb,
                                                        float* __restrict__ xs){
  long long idx = (long long)blockIdx.x * 256 + threadIdx.x;
  int d = (int)(idx & 255);
  long long bl = idx >> 8;
  int l = (int)(bl & 2047);
  const float* base = xz + (bl << 9) + d;
  float w0 = cw[d*4], w1 = cw[d*4+1], w2 = cw[d*4+2], w3 = cw[d*4+3];
  float acc = cb[d] + w3 * base[0];
  if (l >= 1) acc += w2 * base[-512];
  if (l >= 2) acc += w1 * base[-1024];
  if (l >= 3) acc += w0 * base[-1536];
  xs[idx] = acc / (1.0f + expf(-acc));
}

// ---- proj = xs @ W_xp (K=256, N=32); 8 rows per block ---------------------
__global__ __launch_bounds__(256) void gemm_proj(const float* __restrict__ xs,
                                                 const float* __restrict__ W,
                                                 float* __restrict__ proj){
  __shared__ float As[2048];
  long long row0 = (long long)blockIdx.x * 8;
  for (int i = threadIdx.x; i < 2048; i += 256) As[i] = xs[row0 * 256 + i];
  __syncthreads();
  int r = threadIdx.x >> 5, cidx = threadIdx.x & 31;
  float acc = 0.0f;
#pragma unroll 8
  for (int k = 0; k < 256; k++) acc = fmaf(As[r * 256 + k], W[k * 32 + cidx], acc);
  proj[(row0 + r) * 32 + cidx] = acc;
}

// ===== segment-parallel selective scan, dt fused ===========================
__global__ __launch_bounds__(256) void scan1_kernel(const float* __restrict__ xs,
                                                    const float* __restrict__ proj,
                                                    const float* __restrict__ Wdt,
                                                    const float* __restrict__ bdt,
                                                    const float* __restrict__ A_log,
                                                    float* __restrict__ Pb,
                                                    float* __restrict__ Qb){
  __shared__ float pj[64][32];
  int blk = blockIdx.x;
  int seg = blk & 31, b = blk >> 5;
  int d = threadIdx.x;
  long long rowbase = (long long)b * 2048 + seg * 64;
  {
    const float4* src4 = (const float4*)(proj + rowbase * 32);
    float4* dst4 = (float4*)&pj[0][0];
    for (int i = threadIdx.x; i < 512; i += 256) dst4[i] = src4[i];
  }
  __syncthreads();
  float wdt[16];
#pragma unroll
  for (int r = 0; r < 16; r++) wdt[r] = Wdt[r * 256 + d];
  float bd = bdt[d];
  float A[8];
#pragma unroll
  for (int s = 0; s < 8; s++) A[s] = -expf(A_log[d * 8 + s]);
  const float* xp = xs + rowbase * 256 + d;
  float P[8], q[8];
#pragma unroll
  for (int s = 0; s < 8; s++){ P[s] = 1.0f; q[s] = 0.0f; }
  for (int l = 0; l < 64; l++){
    float acc = bd;
#pragma unroll
    for (int r = 0; r < 16; r++) acc = fmaf(pj[l][r], wdt[r], acc);
    float dt = (acc > 0.0f) ? acc + log1pf(expf(-acc)) : log1pf(expf(acc));
    float x = xp[(long long)l * 256];
    float dx = dt * x;
#pragma unroll
    for (int s = 0; s < 8; s++){
      float dA = expf(dt * A[s]);
      P[s] *= dA;
      q[s] = fmaf(dA, q[s], dx * pj[l][16 + s]);
    }
  }
  long long obase = ((long long)blk << 11) + (long long)d * 8;
  *(float4*)(Pb + obase)     = make_float4(P[0], P[1], P[2], P[3]);
  *(float4*)(Pb + obase + 4) = make_float4(P[4], P[5], P[6], P[7]);
  *(float4*)(Qb + obase)     = make_float4(q[0], q[1], q[2], q[3]);
  *(float4*)(Qb + obase + 4) = make_float4(q[4], q[5], q[6], q[7]);
}

__global__ __launch_bounds__(256) void scan2_kernel(const float* __restrict__ Pb,
                                                    const float* __restrict__ Qb,
                                                    float* __restrict__ Hs){
  int t = blockIdx.x * 256 + threadIdx.x;
  int ds_ = t & 2047;
  int b = t >> 11;
  float h = 0.0f;
#pragma unroll
  for (int g = 0; g < 32; g++){
    long long idx = (((long long)b * 32 + g) << 11) + ds_;
    Hs[idx] = h;
    h = fmaf(Pb[idx], h, Qb[idx]);
  }
}

__global__ __launch_bounds__(256) void scan3_kernel(const float* __restrict__ xz,
                                                    float* __restrict__ xs,
                                                    const float* __restrict__ proj,
                                                    const float* __restrict__ Wdt,
                                                    const float* __restrict__ bdt,
                                                    const float* __restrict__ A_log,
                                                    const float* __restrict__ Dsk,
                                                    const float* __restrict__ Hs){
  __shared__ float pj[64][32];
  int blk = blockIdx.x;
  int seg = blk & 31, b = blk >> 5;
  int d = threadIdx.x;
  long long rowbase = (long long)b * 2048 + seg * 64;
  {
    const float4* src4 = (const float4*)(proj + rowbase * 32);
    float4* dst4 = (float4*)&pj[0][0];
    for (int i = threadIdx.x; i < 512; i += 256) dst4[i] = src4[i];
  }
  __syncthreads();
  float wdt[16];
#pragma unroll
  for (int r = 0; r < 16; r++) wdt[r] = Wdt[r * 256 + d];
  float bd = bdt[d];
  float A[8];
#pragma unroll
  for (int s = 0; s < 8; s++) A[s] = -expf(A_log[d * 8 + s]);
  float Dv = Dsk[d];
  long long hbase = ((long long)blk << 11) + (long long)d * 8;
  float4 h0 = *(const float4*)(Hs + hbase);
  float4 h1 = *(const float4*)(Hs + hbase + 4);
  float h[8] = {h0.x, h0.y, h0.z, h0.w, h1.x, h1.y, h1.z, h1.w};
  float* xp = xs + rowbase * 256 + d;
  const float* zp = xz + rowbase * 512 + 256 + d;
  for (int l = 0; l < 64; l++){
    float acc = bd;
#pragma unroll
    for (int r = 0; r < 16; r++) acc = fmaf(pj[l][r], wdt[r], acc);
    float dt = (acc > 0.0f) ? acc + log1pf(expf(-acc)) : log1pf(expf(acc));
    float x = xp[(long long)l * 256];
    float dx = dt * x;
    float y = 0.0f;
#pragma unroll
    for (int s = 0; s < 8; s++){
      float dA = expf(dt * A[s]);
      h[s] = fmaf(dA, h[s], dx * pj[l][16 + s]);
      y = fmaf(h[s], pj[l][24 + s], y);
    }
    y = fmaf(x, Dv, y);
    float z = zp[(long long)l * 512];
    xp[(long long)l * 256] = y * (z / (1.0f + expf(-z)));
  }
}

// ---- layernorm(fq(hres) + fq(y)) : one row per wave ------------------------
__global__ __launch_bounds__(256) void ln_kernel(const float* __restrict__ hraw,
                                                 const float* __restrict__ hslot,
                                                 float* __restrict__ y,
                                                 const float* __restrict__ yslot,
                                                 const float* __restrict__ g,
                                                 const float* __restrict__ bb,
                                                 float* __restrict__ bkt){
  int wid = threadIdx.x >> 6, lane = threadIdx.x & 63;
  long long row = (long long)blockIdx.x * 4 + wid;
  long long o = row * 256 + lane * 4;
  float sh = g_of(hslot[0]);
  float sy = g_of(yslot[0]);
  float4 hv = *(const float4*)(hraw + o);
  float4 yv = *(const float4*)(y + o);
  float t0 = fq_val(hv.x, sh) + fq_val(yv.x, sy);
  float t1 = fq_val(hv.y, sh) + fq_val(yv.y, sy);
  float t2 = fq_val(hv.z, sh) + fq_val(yv.z, sy);
  float t3 = fq_val(hv.w, sh) + fq_val(yv.w, sy);
  float sum = t0 + t1 + t2 + t3;
  for (int m = 32; m; m >>= 1) sum += __shfl_xor(sum, m);
  float mean = sum * (1.0f / 256.0f);
  float d0 = t0 - mean, d1 = t1 - mean, d2 = t2 - mean, d3 = t3 - mean;
  float vs = d0 * d0 + d1 * d1 + d2 * d2 + d3 * d3;
  for (int m = 32; m; m >>= 1) vs += __shfl_xor(vs, m);
  float r = rsqrtf(vs * (1.0f / 256.0f) + 1e-5f);
  float4 gv = *(const float4*)(g + lane * 4);
  float4 bv = *(const float4*)(bb + lane * 4);
  float4 ov;
  ov.x = d0 * r * gv.x + bv.x;
  ov.y = d1 * r * gv.y + bv.y;
  ov.z = d2 * r * gv.z + bv.z;
  ov.w = d3 * r * gv.w + bv.w;
  *(float4*)(y + o) = ov;
  float mx = fmaxf(fmaxf(fabsf(ov.x), fabsf(ov.y)), fmaxf(fabsf(ov.z), fabsf(ov.w)));
  bk_absmax(mx, bkt);
}

// ---- two-stage mean of fq(h) over L ---------------------------------------
__global__ __launch_bounds__(256) void mean_part(const float* __restrict__ h,
                                                 const float* __restrict__ slot,
                                                 float* __restrict__ part){
  int blk = blockIdx.x;
  int d = threadIdx.x;
  int lc = blk & 63, b = blk >> 6;
  float s = g_of(slot[0]);
  const float* p = h + ((long long)b * 2048 + lc * 32) * 256 + d;
  float a = 0.0f;
  for (int l = 0; l < 32; l++) a += fq_val(p[(long long)l * 256], s);
  part[(long long)blk * 256 + d] = a;
}

__global__ __launch_bounds__(256) void mean_fin(const float* __restrict__ part,
                                                float* __restrict__ pooled){
  int idx = blockIdx.x * 256 + threadIdx.x;
  int d = idx & 255, b = idx >> 8;
  float a = 0.0f;
  for (int lc = 0; lc < 64; lc++)
    a += part[((long long)b * 64 + lc) * 256 + d];
  pooled[idx] = a * (1.0f / 2048.0f);
}

__global__ __launch_bounds__(320) void cls_kernel(const float* __restrict__ pooled,
                                                  const float* __restrict__ clsq,
                                                  const float* __restrict__ cb,
                                                  float* __restrict__ out){
  int tid = threadIdx.x;
  if (tid >= 320) return;
  int b = tid / 10, n = tid - b * 10;
  float acc = cb[n];
  const float* pr = pooled + b * 256;
  const float* wr = clsq + n * 256;
  for (int dd = 0; dd < 256; dd++) acc = fmaf(pr[dd], wr[dd], acc);
  out[tid] = acc;
}

// ===========================================================================
extern "C" void kernel_launch(void* const* d_in, const int* in_sizes, int n_in,
                              void* d_out, int out_size, void* d_ws, size_t ws_size,
                              hipStream_t stream) {
  const float* x_in   = (const float*)d_in[0];
  const float* pw_in  = (const float*)d_in[1];
  const float* pb_in  = (const float*)d_in[2];
  const float* pos_in = (const float*)d_in[3];
  const float* Win    = (const float*)d_in[4];
  const float* convw  = (const float*)d_in[5];
  const float* convb  = (const float*)d_in[6];
  const float* Wxp    = (const float*)d_in[7];
  const float* Wdt    = (const float*)d_in[8];
  const float* bdt    = (const float*)d_in[9];
  const float* Alog   = (const float*)d_in[10];
  const float* Dskip  = (const float*)d_in[11];
  const float* Dsk    = Dskip;
  const float* Wout   = (const float*)d_in[12];
  const float* lng    = (const float*)d_in[13];
  const float* lnb    = (const float*)d_in[14];
  const float* clsw   = (const float*)d_in[15];
  const float* clsb   = (const float*)d_in[16];
  float* out = (float*)d_out;

  // -------- workspace layout (floats) --------
  float* W = (float*)d_ws;
  float* sc     = W;                    // 64
  float* bkt    = W + 64;               // 8 × 1024
  float* pwq    = W + 8256;             // 128
  float* clsq   = W + 8384;             // 2,560
  float* pooled = W + 10944;            // 8,192
  float* mpart  = W + 19136;            // 524,288
  float* wsplit_base = W + 543424;      // 786,432 floats of bf16 weight splits
  short* winHs  = (short*)wsplit_base;              // 4*512*256
  short* winLs  = winHs + 524288;
  short* woutHs = winLs + 524288;                   // 4*256*256
  short* woutLs = woutHs + 262144;
  float* hbuf   = wsplit_base + 786432; // 16,777,216
  float* ybuf   = hbuf + 16777216;      // 16,777,216
  float* chunkW = ybuf + 16777216;

  const size_t fixed_f  = 34884288ULL;
  const size_t perseq_f = 1835008ULL;
  int CB = 32;
  while (CB > 1 && (fixed_f + (size_t)CB * perseq_f) * 4 > ws_size) CB >>= 1;
  const long long R = (long long)CB * 2048;
  float* xz_c   = chunkW;
  float* xs_c   = xz_c + R * 512;
  float* proj_c = xs_c + R * 256;
  float* Pb_c   = proj_c + R * 32;
  float* Qb_c   = Pb_c + (long long)CB * 65536;
  float* Hs_c   = Qb_c + (long long)CB * 65536;

  hipMemsetAsync(sc, 0, (64 + 8 * 1024) * sizeof(float), stream);

  // weight split/transpose (bf16 hi+lo)
  wsplit<<<dim3(8, 4, 4), 256, 0, stream>>>(Win, winHs, winLs, 512);
  wsplit<<<dim3(4, 4, 4), 256, 0, stream>>>(Wout, woutHs, woutLs, 256);

  absmax_b<<<2048, 256, 0, stream>>>(x_in, 2097152LL, bkt + 0 * 1024);
  combine_kernel<<<1, 64, 0, stream>>>(bkt + 0 * 1024, sc + 0);
  fq_small<<<1, 256, 0, stream>>>(pw_in, pwq, 128);
  patchify_kernel<<<16384, 256, 0, stream>>>(x_in, pwq, pb_in, hbuf, sc + 0,
                                             bkt + 1 * 1024);
  combine_kernel<<<1, 64, 0, stream>>>(bkt + 1 * 1024, sc + 1);
  absmax_b<<<1024, 256, 0, stream>>>(pos_in, 524288LL, bkt + 2 * 1024);
  combine_kernel<<<1, 64, 0, stream>>>(bkt + 2 * 1024, sc + 4);
  chain_kernel<<<1, 64, 0, stream>>>(sc);
  addpos_kernel<<<16384, 256, 0, stream>>>(hbuf, pos_in, sc, bkt + 3 * 1024);
  combine_kernel<<<1, 64, 0, stream>>>(bkt + 3 * 1024, sc + 7);

  for (int i = 0; i < 2; i++){
    float* hin = (i == 0) ? hbuf : ybuf;
    float* yac = (i == 0) ? ybuf : hbuf;
    float* hs  = sc + (i == 0 ? 7 : 9);
    float* ys  = sc + (i == 0 ? 8 : 10);
    float* ybk = bkt + (i == 0 ? 4 : 6) * 1024;
    float* hbk = bkt + (i == 0 ? 5 : 7) * 1024;
    for (int dir = 0; dir < 2; dir++){
      int idx = i * 2 + dir;
      for (int b0 = 0; b0 < 32; b0 += CB){
        const float* hA = hin + (long long)b0 * 524288;
        float*       yC = yac + (long long)b0 * 524288;
        // xz = fq(u)(flip?) @ W_in  -> MFMA qmode (R x 512)
        gemm_mfma<<<dim3(4, R / 128), 256, 0, stream>>>(
            hA, winHs + (long long)idx * 131072, winLs + (long long)idx * 131072,
            xz_c, 512, dir, 0, 0, 1, hs, nullptr);
        conv_silu_kernel<<<R, 256, 0, stream>>>(xz_c, convw + idx * 1024,
                                                convb + idx * 256, xs_c);
        gemm_proj<<<R / 8, 256, 0, stream>>>(xs_c, Wxp + idx * 8192, proj_c);
        scan1_kernel<<<CB * 32, 256, 0, stream>>>(xs_c, proj_c,
                                                  Wdt + idx * 4096, bdt + idx * 256,
                                                  Alog + idx * 2048, Pb_c, Qb_c);
        scan2_kernel<<<CB * 8, 256, 0, stream>>>(Pb_c, Qb_c, Hs_c);
        scan3_kernel<<<CB * 32, 256, 0, stream>>>(xz_c, xs_c, proj_c,
                                                  Wdt + idx * 4096, bdt + idx * 256,
                                                  Alog + idx * 2048,
                                                  Dsk + idx * 256, Hs_c);
        // yac (+=flip) = xs @ W_out -> MFMA split mode (R x 256)
        gemm_mfma<<<dim3(2, R / 128), 256, 0, stream>>>(
            xs_c, woutHs + (long long)idx * 65536, woutLs + (long long)idx * 65536,
            yC, 256, 0, dir, dir, 0, nullptr, dir ? ybk : nullptr);
      }
    }
    combine_kernel<<<1, 64, 0, stream>>>(ybk, ys);
    ln_kernel<<<16384, 256, 0, stream>>>(hin, hs, yac, ys, lng + i * 256,
                                         lnb + i * 256, hbk);
    combine_kernel<<<1, 64, 0, stream>>>(hbk, sc + (i == 0 ? 9 : 11));
  }
  mean_part<<<2048, 256, 0, stream>>>(hbuf, sc + 11, mpart);
  mean_fin<<<32, 256, 0, stream>>>(mpart, pooled);
  fq_small<<<1, 256, 0, stream>>>(pooled, pooled, 8192);
  fq_small<<<1, 256, 0, stream>>>(clsw, clsq, 2560);
  cls_kernel<<<1, 320, 0, stream>>>(pooled, clsq, clsb, out);
}

// Round 7
// 1837.164 us; speedup vs baseline: 7.8056x; 1.5561x over previous
//
#include <hip/hip_runtime.h>

// ---------------------------------------------------------------------------
// FEMBA full forward. Shapes fixed: B=32, L=2048, D=256, di=256, ds=8, dtr=16,
// K=4, nb=2, dirs=2, nc=10.
// Round 7: fast transcendentals in scans, seg 64->32 (+Hs aliases Pb),
// conv+silu+proj fused, xc/z split from W_in GEMM, scan3 emits packed bf16
// hi/lo y for the W_out MFMA GEMM, integer-granular batch chunking.
// ---------------------------------------------------------------------------

typedef __attribute__((ext_vector_type(8))) short bfrag;   // 8 bf16
typedef __attribute__((ext_vector_type(4))) float cfrag;   // 4 f32 acc

__device__ __forceinline__ float fq_val(float x, float s){
  float q = rintf(x / s);
  q = fminf(fmaxf(q, -128.0f), 127.0f);
  return q * s;
}
__device__ __forceinline__ float g_of(float a){ return fmaxf(a, 1e-8f) / 127.0f; }

__device__ __forceinline__ short f2bf(float f){           // RNE f32->bf16 bits
  unsigned u = __float_as_uint(f);
  u += 0x7fff + ((u >> 16) & 1);
  return (short)(u >> 16);
}
__device__ __forceinline__ float bf2f(short h){
  return __uint_as_float(((unsigned)(unsigned short)h) << 16);
}

__device__ __forceinline__ void bk_absmax(float v, float* bkt){
  for (int m = 32; m; m >>= 1) v = fmaxf(v, __shfl_xor(v, m));
  __shared__ float wmax[4];
  int lane = threadIdx.x & 63, wid = threadIdx.x >> 6;
  if (lane == 0) wmax[wid] = v;
  __syncthreads();
  if (threadIdx.x == 0){
    float m = fmaxf(fmaxf(wmax[0], wmax[1]), fmaxf(wmax[2], wmax[3]));
    atomicMax((unsigned int*)&bkt[(blockIdx.x & 63) * 16], __float_as_uint(m));
  }
}

__global__ __launch_bounds__(256) void absmax_b(const float* __restrict__ x,
                                                long long n, float* __restrict__ bkt){
  float m = 0.0f;
  for (long long i = (long long)blockIdx.x * 256 + threadIdx.x; i < n;
       i += (long long)gridDim.x * 256)
    m = fmaxf(m, fabsf(x[i]));
  bk_absmax(m, bkt);
}

__global__ __launch_bounds__(64) void combine_kernel(const float* __restrict__ bkt,
                                                     float* __restrict__ slot){
  float v = bkt[(threadIdx.x & 63) * 16];
  for (int m = 32; m; m >>= 1) v = fmaxf(v, __shfl_xor(v, m));
  if (threadIdx.x == 0) slot[0] = v;
}

__global__ __launch_bounds__(64) void chain_kernel(float* __restrict__ sc){
  if (threadIdx.x == 0){
    float s1 = g_of(sc[1]);
    float a1 = fq_val(sc[1], s1);
    sc[2] = s1; sc[3] = g_of(a1);
    float p1 = g_of(sc[4]);
    float a2 = fq_val(sc[4], p1);
    sc[5] = p1; sc[6] = g_of(a2);
  }
}

__global__ __launch_bounds__(256) void fq_small(const float* __restrict__ src,
                                                float* __restrict__ dst, int n){
  __shared__ float red[256];
  __shared__ float sS;
  float m = 0.0f;
  for (int i = threadIdx.x; i < n; i += 256) m = fmaxf(m, fabsf(src[i]));
  red[threadIdx.x] = m; __syncthreads();
  for (int s2 = 128; s2 > 0; s2 >>= 1){
    if (threadIdx.x < s2) red[threadIdx.x] = fmaxf(red[threadIdx.x], red[threadIdx.x + s2]);
    __syncthreads();
  }
  if (threadIdx.x == 0) sS = g_of(red[0]);
  __syncthreads();
  float s = sS;
  for (int i = threadIdx.x; i < n; i += 256) dst[i] = fq_val(src[i], s);
}

// ---- weight split+transpose: W[k][n] f32 -> WhT[n][k], WlT[n][k] bf16 -----
__global__ __launch_bounds__(256) void wsplit(const float* __restrict__ src,
                                              short* __restrict__ dh,
                                              short* __restrict__ dl, int N){
  __shared__ float tile[64][65];
  int n0 = blockIdx.x * 64, k0 = blockIdx.y * 64, id = blockIdx.z;
  const float* S = src + (long long)id * 256 * N;
  short* H = dh + (long long)id * N * 256;
  short* L = dl + (long long)id * N * 256;
  int t = threadIdx.x;
#pragma unroll
  for (int i = 0; i < 16; i++){
    int idx = i * 256 + t;
    int kr = idx >> 6, nc = idx & 63;
    tile[kr][nc] = S[(long long)(k0 + kr) * N + n0 + nc];
  }
  __syncthreads();
#pragma unroll
  for (int i = 0; i < 16; i++){
    int idx = i * 256 + t;
    int nr = idx >> 6, kc = idx & 63;
    float f = tile[kc][nr];
    short h = f2bf(f);
    short l = f2bf(f - bf2f(h));
    H[(long long)(n0 + nr) * 256 + k0 + kc] = h;
    L[(long long)(n0 + nr) * 256 + k0 + kc] = l;
  }
}

// ---- patchify (x4 vectorized) + inline fq(x) + bucketed absmax ------------
__global__ __launch_bounds__(256) void patchify_kernel(const float* __restrict__ x,
                                                       const float* __restrict__ pwq,
                                                       const float* __restrict__ pb,
                                                       float* __restrict__ h,
                                                       const float* __restrict__ slot,
                                                       float* __restrict__ bkt){
  int t = blockIdx.x * 256 + threadIdx.x;
  int q = t & 63;
  int l = (t >> 6) & 2047;
  int b = t >> 17;
  int d0 = q * 4;
  int c0 = d0 & 31, g = d0 >> 5;
  float s = g_of(slot[0]);
  const float* xp = x + ((long long)(b * 16 + 2 * g) * 4096 + 2 * l);
  float x0 = fq_val(xp[0], s),    x1 = fq_val(xp[1], s);
  float x2 = fq_val(xp[4096], s), x3 = fq_val(xp[4097], s);
  float4 o; float* op = (float*)&o;
  float mx = 0.0f;
#pragma unroll
  for (int j = 0; j < 4; j++){
    int c = c0 + j;
    float a = pb[c] + x0 * pwq[c * 4] + x1 * pwq[c * 4 + 1]
                    + x2 * pwq[c * 4 + 2] + x3 * pwq[c * 4 + 3];
    op[j] = a; mx = fmaxf(mx, fabsf(a));
  }
  *(float4*)(h + (long long)t * 4) = o;
  bk_absmax(mx, bkt);
}

__global__ __launch_bounds__(256) void addpos_kernel(float* __restrict__ h,
                                                     const float* __restrict__ pos,
                                                     const float* __restrict__ sc,
                                                     float* __restrict__ bkt){
  long long t = (long long)blockIdx.x * 256 + threadIdx.x;
  float s1 = sc[2], s2 = sc[3], p1 = sc[5], p2 = sc[6];
  float4 hv = *(const float4*)(h + t * 4);
  float4 pv = *(const float4*)(pos + ((t * 4) & 524287));
  float* hp = (float*)&hv; float* pp = (float*)&pv;
  float4 o; float* op = (float*)&o;
  float mx = 0.0f;
#pragma unroll
  for (int j = 0; j < 4; j++){
    float v = fq_val(fq_val(hp[j], s1), s2) + fq_val(fq_val(pp[j], p1), p2);
    op[j] = v; mx = fmaxf(mx, fabsf(v));
  }
  *(float4*)(h + t * 4) = o;
  bk_absmax(mx, bkt);
}

// ---- W_in MFMA GEMM: [xc|z](R x 512) = fq(A)(R,256) @ B(256,512) ----------
// A fq'd on read -> integer Q (exact bf16); out = sA*(Q@Bh + Q@Bl).
// Block 128x128, 4 waves 2x2, wave 64x64 = 4x4 mfma_16x16x32. bn<2 -> xc,
// bn>=2 -> z (each row-stride 256).
__global__ __launch_bounds__(256) void gemm_win(const float* __restrict__ A,
                                                const short* __restrict__ BhT,
                                                const short* __restrict__ BlT,
                                                float* __restrict__ Cx,
                                                float* __restrict__ Cz,
                                                int flipA,
                                                const float* __restrict__ aslot){
  __shared__ short Ah[128][40];
  __shared__ short Bh[128][40];
  __shared__ short Bl[128][40];
  int t = threadIdx.x;
  int bn = blockIdx.x, bm = blockIdx.y;
  int lane = t & 63, wv = t >> 6;
  int wm = wv & 1, wn = wv >> 1;
  int qd = lane >> 4, l16 = lane & 15;
  float sA = g_of(aslot[0]);

  cfrag acc[4][4];
#pragma unroll
  for (int i = 0; i < 4; i++)
#pragma unroll
    for (int j = 0; j < 4; j++)
      acc[i][j] = (cfrag){0.f, 0.f, 0.f, 0.f};

  for (int k0 = 0; k0 < 256; k0 += 32){
#pragma unroll
    for (int i = 0; i < 4; i++){
      int idx = i * 256 + t;
      int row = idx >> 3, c4 = (idx & 7) * 4;
      int mg = bm * 128 + row;
      long long mr = flipA ? (((long long)(mg >> 11)) << 11) + (2047 - (mg & 2047)) : mg;
      float4 v = *(const float4*)(A + mr * 256 + k0 + c4);
      float* vp = (float*)&v;
#pragma unroll
      for (int j = 0; j < 4; j++){
        float qv = fminf(fmaxf(rintf(vp[j] / sA), -128.0f), 127.0f);
        Ah[row][c4 + j] = f2bf(qv);
      }
    }
#pragma unroll
    for (int i = 0; i < 2; i++){
      int idx = i * 256 + t;
      int row = idx >> 2, c8 = (idx & 3) * 8;
      long long go = (long long)(bn * 128 + row) * 256 + k0 + c8;
      *(bfrag*)&Bh[row][c8] = *(const bfrag*)(BhT + go);
      *(bfrag*)&Bl[row][c8] = *(const bfrag*)(BlT + go);
    }
    __syncthreads();

    bfrag bh[4], bl[4];
#pragma unroll
    for (int ni = 0; ni < 4; ni++){
      bh[ni] = *(const bfrag*)&Bh[wn * 64 + ni * 16 + l16][qd * 8];
      bl[ni] = *(const bfrag*)&Bl[wn * 64 + ni * 16 + l16][qd * 8];
    }
#pragma unroll
    for (int mi = 0; mi < 4; mi++){
      bfrag ah = *(const bfrag*)&Ah[wm * 64 + mi * 16 + l16][qd * 8];
#pragma unroll
      for (int ni = 0; ni < 4; ni++){
        acc[mi][ni] = __builtin_amdgcn_mfma_f32_16x16x32_bf16(ah, bh[ni], acc[mi][ni], 0, 0, 0);
        acc[mi][ni] = __builtin_amdgcn_mfma_f32_16x16x32_bf16(ah, bl[ni], acc[mi][ni], 0, 0, 0);
      }
    }
    __syncthreads();
  }

  float* Co = (bn < 2) ? Cx : Cz;
  int cb = (bn & 1) * 128;
#pragma unroll
  for (int mi = 0; mi < 4; mi++){
#pragma unroll
    for (int ni = 0; ni < 4; ni++){
      int colg = cb + wn * 64 + ni * 16 + l16;
#pragma unroll
      for (int r = 0; r < 4; r++){
        long long mg = bm * 128 + wm * 64 + mi * 16 + qd * 4 + r;
        Co[mg * 256 + colg] = acc[mi][ni][r] * sA;
      }
    }
  }
}

// ---- W_out MFMA GEMM: C(R,256) (+=flip) = A(R,256) @ B(256,256) -----------
// A is packed bf16 hi|lo<<16 per element (written by scan3).
__global__ __launch_bounds__(256) void gemm_wout(const float* __restrict__ A,
                                                 const short* __restrict__ BhT,
                                                 const short* __restrict__ BlT,
                                                 float* __restrict__ C,
                                                 int flipC, int accum,
                                                 float* __restrict__ bkt){
  __shared__ short Ah[128][40];
  __shared__ short Al[128][40];
  __shared__ short Bh[128][40];
  __shared__ short Bl[128][40];
  int t = threadIdx.x;
  int bn = blockIdx.x, bm = blockIdx.y;
  int lane = t & 63, wv = t >> 6;
  int wm = wv & 1, wn = wv >> 1;
  int qd = lane >> 4, l16 = lane & 15;

  cfrag acc[4][4];
#pragma unroll
  for (int i = 0; i < 4; i++)
#pragma unroll
    for (int j = 0; j < 4; j++)
      acc[i][j] = (cfrag){0.f, 0.f, 0.f, 0.f};

  for (int k0 = 0; k0 < 256; k0 += 32){
#pragma unroll
    for (int i = 0; i < 4; i++){
      int idx = i * 256 + t;
      int row = idx >> 3, c4 = (idx & 7) * 4;
      long long mg = (long long)bm * 128 + row;
      float4 v = *(const float4*)(A + mg * 256 + k0 + c4);
      unsigned* up = (unsigned*)&v;
#pragma unroll
      for (int j = 0; j < 4; j++){
        Ah[row][c4 + j] = (short)(up[j] & 0xffff);
        Al[row][c4 + j] = (short)(up[j] >> 16);
      }
    }
#pragma unroll
    for (int i = 0; i < 2; i++){
      int idx = i * 256 + t;
      int row = idx >> 2, c8 = (idx & 3) * 8;
      long long go = (long long)(bn * 128 + row) * 256 + k0 + c8;
      *(bfrag*)&Bh[row][c8] = *(const bfrag*)(BhT + go);
      *(bfrag*)&Bl[row][c8] = *(const bfrag*)(BlT + go);
    }
    __syncthreads();

    bfrag bh[4], bl[4];
#pragma unroll
    for (int ni = 0; ni < 4; ni++){
      bh[ni] = *(const bfrag*)&Bh[wn * 64 + ni * 16 + l16][qd * 8];
      bl[ni] = *(const bfrag*)&Bl[wn * 64 + ni * 16 + l16][qd * 8];
    }
#pragma unroll
    for (int mi = 0; mi < 4; mi++){
      bfrag ah = *(const bfrag*)&Ah[wm * 64 + mi * 16 + l16][qd * 8];
      bfrag al = *(const bfrag*)&Al[wm * 64 + mi * 16 + l16][qd * 8];
#pragma unroll
      for (int ni = 0; ni < 4; ni++){
        acc[mi][ni] = __builtin_amdgcn_mfma_f32_16x16x32_bf16(ah, bh[ni], acc[mi][ni], 0, 0, 0);
        acc[mi][ni] = __builtin_amdgcn_mfma_f32_16x16x32_bf16(al, bh[ni], acc[mi][ni], 0, 0, 0);
        acc[mi][ni] = __builtin_amdgcn_mfma_f32_16x16x32_bf16(ah, bl[ni], acc[mi][ni], 0, 0, 0);
      }
    }
    __syncthreads();
  }

  float mx = 0.0f;
#pragma unroll
  for (int mi = 0; mi < 4; mi++){
#pragma unroll
    for (int ni = 0; ni < 4; ni++){
      int colg = bn * 128 + wn * 64 + ni * 16 + l16;
#pragma unroll
      for (int r = 0; r < 4; r++){
        int mg = bm * 128 + wm * 64 + mi * 16 + qd * 4 + r;
        long long mr = flipC ? (((long long)(mg >> 11)) << 11) + (2047 - (mg & 2047)) : mg;
        float* Cp = C + mr * 256 + colg;
        if (accum){
          float nv = *Cp + acc[mi][ni][r];
          *Cp = nv;
          mx = fmaxf(mx, fabsf(nv));
        } else {
          *Cp = acc[mi][ni][r];
        }
      }
    }
  }
  if (bkt) bk_absmax(mx, bkt);
}

// ---- fused depthwise causal conv(K=4) + SiLU + proj = xs @ W_xp -----------
// block = 8 rows (same sequence); thread owns channel d.
__global__ __launch_bounds__(256) void conv_proj(const float* __restrict__ xc,
                                                 const float* __restrict__ cw,
                                                 const float* __restrict__ cb,
                                                 const float* __restrict__ Wxp,
                                                 float* __restrict__ xs,
                                                 float* __restrict__ proj){
  __shared__ float As[8][256];
  long long r0 = (long long)blockIdx.x * 8;
  int l0 = (int)(r0 & 2047);
  int d = threadIdx.x;
  float w0 = cw[d*4], w1 = cw[d*4+1], w2 = cw[d*4+2], w3 = cw[d*4+3];
  float cbd = cb[d];
  const float* base = xc + r0 * 256 + d;
  float vm3 = (l0 >= 3) ? base[-768] : 0.0f;
  float vm2 = (l0 >= 2) ? base[-512] : 0.0f;
  float vm1 = (l0 >= 1) ? base[-256] : 0.0f;
#pragma unroll
  for (int r = 0; r < 8; r++){
    float v0 = base[r * 256];
    float a = cbd + w3 * v0 + w2 * vm1 + w1 * vm2 + w0 * vm3;
    float sv = __fdividef(a, 1.0f + __expf(-a));
    As[r][d] = sv;
    xs[r0 * 256 + r * 256 + d] = sv;
    vm3 = vm2; vm2 = vm1; vm1 = v0;
  }
  __syncthreads();
  int rr = threadIdx.x >> 5, cc = threadIdx.x & 31;
  float acc = 0.0f;
#pragma unroll 8
  for (int k = 0; k < 256; k++) acc = fmaf(As[rr][k], Wxp[k * 32 + cc], acc);
  proj[(r0 + rr) * 32 + cc] = acc;
}

// ===== segment-parallel selective scan: 64 segments of 32 per sequence =====
// scan1: per-segment (P = prod dA, q = scan h0=0); dt recomputed from proj.
__global__ __launch_bounds__(256) void scan1_kernel(const float* __restrict__ xs,
                                                    const float* __restrict__ proj,
                                                    const float* __restrict__ Wdt,
                                                    const float* __restrict__ bdt,
                                                    const float* __restrict__ A_log,
                                                    float* __restrict__ Pb,
                                                    float* __restrict__ Qb){
  __shared__ float pj[32][32];
  int blk = blockIdx.x;
  int seg = blk & 63, b = blk >> 6;
  int d = threadIdx.x;
  long long rowbase = (long long)b * 2048 + seg * 32;
  {
    const float4* src4 = (const float4*)(proj + rowbase * 32);
    float4* dst4 = (float4*)&pj[0][0];
    if (threadIdx.x < 256) dst4[threadIdx.x] = src4[threadIdx.x];
  }
  __syncthreads();
  float wdt[16];
#pragma unroll
  for (int r = 0; r < 16; r++) wdt[r] = Wdt[r * 256 + d];
  float bd = bdt[d];
  float A[8];
#pragma unroll
  for (int s = 0; s < 8; s++) A[s] = -expf(A_log[d * 8 + s]);
  const float* xp = xs + rowbase * 256 + d;
  float P[8], q[8];
#pragma unroll
  for (int s = 0; s < 8; s++){ P[s] = 1.0f; q[s] = 0.0f; }
  for (int l = 0; l < 32; l++){
    float acc = bd;
#pragma unroll
    for (int r = 0; r < 16; r++) acc = fmaf(pj[l][r], wdt[r], acc);
    float e = __expf(-fabsf(acc));
    float dt = fmaxf(acc, 0.0f) + __logf(1.0f + e);
    float x = xp[(long long)l * 256];
    float dx = dt * x;
#pragma unroll
    for (int s = 0; s < 8; s++){
      float dA = __expf(dt * A[s]);
      P[s] *= dA;
      q[s] = fmaf(dA, q[s], dx * pj[l][16 + s]);
    }
  }
  long long obase = ((long long)blk << 11) + (long long)d * 8;
  *(float4*)(Pb + obase)     = make_float4(P[0], P[1], P[2], P[3]);
  *(float4*)(Pb + obase + 4) = make_float4(P[4], P[5], P[6], P[7]);
  *(float4*)(Qb + obase)     = make_float4(q[0], q[1], q[2], q[3]);
  *(float4*)(Qb + obase + 4) = make_float4(q[4], q[5], q[6], q[7]);
}

// scan2: serial prefix over 64 segments; Hs overwrites Pb in place.
__global__ __launch_bounds__(256) void scan2_kernel(float* __restrict__ Pb,
                                                    const float* __restrict__ Qb){
  int t = blockIdx.x * 256 + threadIdx.x;   // rows*2048
  int ds_ = t & 2047;
  int b = t >> 11;
  float h = 0.0f;
#pragma unroll
  for (int g = 0; g < 64; g++){
    long long idx = (((long long)b * 64 + g) << 11) + ds_;
    float tp = Pb[idx];
    Pb[idx] = h;                            // Hs
    h = fmaf(tp, h, Qb[idx]);
  }
}

// scan3: thread owns d; 8 h-states in regs; writes packed bf16 hi/lo y.
__global__ __launch_bounds__(256) void scan3_kernel(const float* __restrict__ z,
                                                    float* __restrict__ xs,
                                                    const float* __restrict__ proj,
                                                    const float* __restrict__ Wdt,
                                                    const float* __restrict__ bdt,
                                                    const float* __restrict__ A_log,
                                                    const float* __restrict__ Dsk,
                                                    const float* __restrict__ Hs){
  __shared__ float pj[32][32];
  int blk = blockIdx.x;
  int seg = blk & 63, b = blk >> 6;
  int d = threadIdx.x;
  long long rowbase = (long long)b * 2048 + seg * 32;
  {
    const float4* src4 = (const float4*)(proj + rowbase * 32);
    float4* dst4 = (float4*)&pj[0][0];
    if (threadIdx.x < 256) dst4[threadIdx.x] = src4[threadIdx.x];
  }
  __syncthreads();
  float wdt[16];
#pragma unroll
  for (int r = 0; r < 16; r++) wdt[r] = Wdt[r * 256 + d];
  float bd = bdt[d];
  float A[8];
#pragma unroll
  for (int s = 0; s < 8; s++) A[s] = -expf(A_log[d * 8 + s]);
  float Dv = Dsk[d];
  long long hbase = ((long long)blk << 11) + (long long)d * 8;
  float4 h0 = *(const float4*)(Hs + hbase);
  float4 h1 = *(const float4*)(Hs + hbase + 4);
  float h[8] = {h0.x, h0.y, h0.z, h0.w, h1.x, h1.y, h1.z, h1.w};
  float* xp = xs + rowbase * 256 + d;
  const float* zp = z + rowbase * 256 + d;
  for (int l = 0; l < 32; l++){
    float acc = bd;
#pragma unroll
    for (int r = 0; r < 16; r++) acc = fmaf(pj[l][r], wdt[r], acc);
    float e = __expf(-fabsf(acc));
    float dt = fmaxf(acc, 0.0f) + __logf(1.0f + e);
    float x = xp[(long long)l * 256];
    float dx = dt * x;
    float y = 0.0f;
#pragma unroll
    for (int s = 0; s < 8; s++){
      float dA = __expf(dt * A[s]);
      h[s] = fmaf(dA, h[s], dx * pj[l][16 + s]);
      y = fmaf(h[s], pj[l][24 + s], y);
    }
    y = fmaf(x, Dv, y);
    float zv = zp[(long long)l * 256];
    float yg = y * __fdividef(zv, 1.0f + __expf(-zv));
    short hh = f2bf(yg);
    short ll = f2bf(yg - bf2f(hh));
    xp[(long long)l * 256] =
        __uint_as_float(((unsigned)(unsigned short)ll << 16) | (unsigned short)hh);
  }
}

// ---- layernorm(fq(hres) + fq(y)) : one row per wave ------------------------
__global__ __launch_bounds__(256) void ln_kernel(const float* __restrict__ hraw,
                                                 const float* __restrict__ hslot,
                                                 float* __restrict__ y,
                                                 const float* __restrict__ yslot,
                                                 const float* __restrict__ g,
                                                 const float* __restrict__ bb,
                                                 float* __restrict__ bkt){
  int wid = threadIdx.x >> 6, lane = threadIdx.x & 63;
  long long row = (long long)blockIdx.x * 4 + wid;
  long long o = row * 256 + lane * 4;
  float sh = g_of(hslot[0]);
  float sy = g_of(yslot[0]);
  float4 hv = *(const float4*)(hraw + o);
  float4 yv = *(const float4*)(y + o);
  float t0 = fq_val(hv.x, sh) + fq_val(yv.x, sy);
  float t1 = fq_val(hv.y, sh) + fq_val(yv.y, sy);
  float t2 = fq_val(hv.z, sh) + fq_val(yv.z, sy);
  float t3 = fq_val(hv.w, sh) + fq_val(yv.w, sy);
  float sum = t0 + t1 + t2 + t3;
  for (int m = 32; m; m >>= 1) sum += __shfl_xor(sum, m);
  float mean = sum * (1.0f / 256.0f);
  float d0 = t0 - mean, d1 = t1 - mean, d2 = t2 - mean, d3 = t3 - mean;
  float vs = d0 * d0 + d1 * d1 + d2 * d2 + d3 * d3;
  for (int m = 32; m; m >>= 1) vs += __shfl_xor(vs, m);
  float r = rsqrtf(vs * (1.0f / 256.0f) + 1e-5f);
  float4 gv = *(const float4*)(g + lane * 4);
  float4 bv = *(const float4*)(bb + lane * 4);
  float4 ov;
  ov.x = d0 * r * gv.x + bv.x;
  ov.y = d1 * r * gv.y + bv.y;
  ov.z = d2 * r * gv.z + bv.z;
  ov.w = d3 * r * gv.w + bv.w;
  *(float4*)(y + o) = ov;
  float mx = fmaxf(fmaxf(fabsf(ov.x), fabsf(ov.y)), fmaxf(fabsf(ov.z), fabsf(ov.w)));
  bk_absmax(mx, bkt);
}

// ---- two-stage mean of fq(h) over L ---------------------------------------
__global__ __launch_bounds__(256) void mean_part(const float* __restrict__ h,
                                                 const float* __restrict__ slot,
                                                 float* __restrict__ part){
  int blk = blockIdx.x;
  int d = threadIdx.x;
  int lc = blk & 63, b = blk >> 6;
  float s = g_of(slot[0]);
  const float* p = h + ((long long)b * 2048 + lc * 32) * 256 + d;
  float a = 0.0f;
  for (int l = 0; l < 32; l++) a += fq_val(p[(long long)l * 256], s);
  part[(long long)blk * 256 + d] = a;
}

__global__ __launch_bounds__(256) void mean_fin(const float* __restrict__ part,
                                                float* __restrict__ pooled){
  int idx = blockIdx.x * 256 + threadIdx.x;
  int d = idx & 255, b = idx >> 8;
  float a = 0.0f;
  for (int lc = 0; lc < 64; lc++)
    a += part[((long long)b * 64 + lc) * 256 + d];
  pooled[idx] = a * (1.0f / 2048.0f);
}

__global__ __launch_bounds__(320) void cls_kernel(const float* __restrict__ pooled,
                                                  const float* __restrict__ clsq,
                                                  const float* __restrict__ cb,
                                                  float* __restrict__ out){
  int tid = threadIdx.x;
  if (tid >= 320) return;
  int b = tid / 10, n = tid - b * 10;
  float acc = cb[n];
  const float* pr = pooled + b * 256;
  const float* wr = clsq + n * 256;
  for (int dd = 0; dd < 256; dd++) acc = fmaf(pr[dd], wr[dd], acc);
  out[tid] = acc;
}

// ===========================================================================
extern "C" void kernel_launch(void* const* d_in, const int* in_sizes, int n_in,
                              void* d_out, int out_size, void* d_ws, size_t ws_size,
                              hipStream_t stream) {
  const float* x_in   = (const float*)d_in[0];
  const float* pw_in  = (const float*)d_in[1];
  const float* pb_in  = (const float*)d_in[2];
  const float* pos_in = (const float*)d_in[3];
  const float* Win    = (const float*)d_in[4];
  const float* convw  = (const float*)d_in[5];
  const float* convb  = (const float*)d_in[6];
  const float* Wxp    = (const float*)d_in[7];
  const float* Wdt    = (const float*)d_in[8];
  const float* bdt    = (const float*)d_in[9];
  const float* Alog   = (const float*)d_in[10];
  const float* Dsk    = (const float*)d_in[11];
  const float* Wout   = (const float*)d_in[12];
  const float* lng    = (const float*)d_in[13];
  const float* lnb    = (const float*)d_in[14];
  const float* clsw   = (const float*)d_in[15];
  const float* clsb   = (const float*)d_in[16];
  float* out = (float*)d_out;

  // -------- workspace layout (floats) --------
  float* W = (float*)d_ws;
  float* sc     = W;                    // 64
  float* bkt    = W + 64;               // 8 x 1024
  float* pwq    = W + 8256;             // 128
  float* clsq   = W + 8384;             // 2,560
  float* pooled = W + 10944;            // 8,192
  float* wsplit_base = W + 19136;       // 786,432 (bf16 weight splits)
  short* winHs  = (short*)wsplit_base;
  short* winLs  = winHs + 524288;
  short* woutHs = winLs + 524288;
  short* woutLs = woutHs + 262144;
  float* hbuf   = wsplit_base + 786432; // 16,777,216
  float* ybuf   = hbuf + 16777216;      // 16,777,216
  float* chunkW = ybuf + 16777216;
  float* mpart  = chunkW;               // reused after chunk loop (524,288)

  const size_t fixed_f  = 34360000ULL;
  const size_t perseq_f = 1900544ULL;   // xc+z+xs+proj + Pb+Qb (seg=32)
  long long avail = (long long)(ws_size / 4) - (long long)fixed_f;
  int CB = (int)(avail / (long long)perseq_f);
  if (CB > 32) CB = 32;
  if (CB < 1) CB = 1;

  hipMemsetAsync(sc, 0, (64 + 8 * 1024) * sizeof(float), stream);

  wsplit<<<dim3(8, 4, 4), 256, 0, stream>>>(Win, winHs, winLs, 512);
  wsplit<<<dim3(4, 4, 4), 256, 0, stream>>>(Wout, woutHs, woutLs, 256);

  absmax_b<<<2048, 256, 0, stream>>>(x_in, 2097152LL, bkt + 0 * 1024);
  combine_kernel<<<1, 64, 0, stream>>>(bkt + 0 * 1024, sc + 0);
  fq_small<<<1, 256, 0, stream>>>(pw_in, pwq, 128);
  patchify_kernel<<<16384, 256, 0, stream>>>(x_in, pwq, pb_in, hbuf, sc + 0,
                                             bkt + 1 * 1024);
  combine_kernel<<<1, 64, 0, stream>>>(bkt + 1 * 1024, sc + 1);
  absmax_b<<<1024, 256, 0, stream>>>(pos_in, 524288LL, bkt + 2 * 1024);
  combine_kernel<<<1, 64, 0, stream>>>(bkt + 2 * 1024, sc + 4);
  chain_kernel<<<1, 64, 0, stream>>>(sc);
  addpos_kernel<<<16384, 256, 0, stream>>>(hbuf, pos_in, sc, bkt + 3 * 1024);
  combine_kernel<<<1, 64, 0, stream>>>(bkt + 3 * 1024, sc + 7);

  for (int i = 0; i < 2; i++){
    float* hin = (i == 0) ? hbuf : ybuf;
    float* yac = (i == 0) ? ybuf : hbuf;
    float* hs  = sc + (i == 0 ? 7 : 9);
    float* ys  = sc + (i == 0 ? 8 : 10);
    float* ybk = bkt + (i == 0 ? 4 : 6) * 1024;
    float* hbk = bkt + (i == 0 ? 5 : 7) * 1024;
    for (int dir = 0; dir < 2; dir++){
      int idx = i * 2 + dir;
      for (int b0 = 0; b0 < 32; ){
        int rows = (32 - b0 < CB) ? (32 - b0) : CB;
        long long R = (long long)rows * 2048;
        float* xc_c   = chunkW;
        float* z_c    = xc_c + R * 256;
        float* xs_c   = z_c + R * 256;
        float* proj_c = xs_c + R * 256;
        float* Pb_c   = proj_c + R * 32;
        float* Qb_c   = Pb_c + (long long)rows * 131072;
        const float* hA = hin + (long long)b0 * 524288;
        float*       yC = yac + (long long)b0 * 524288;

        gemm_win<<<dim3(4, R / 128), 256, 0, stream>>>(
            hA, winHs + (long long)idx * 131072, winLs + (long long)idx * 131072,
            xc_c, z_c, dir, hs);
        conv_proj<<<R / 8, 256, 0, stream>>>(xc_c, convw + idx * 1024,
                                             convb + idx * 256, Wxp + idx * 8192,
                                             xs_c, proj_c);
        scan1_kernel<<<rows * 64, 256, 0, stream>>>(xs_c, proj_c,
                                                    Wdt + idx * 4096, bdt + idx * 256,
                                                    Alog + idx * 2048, Pb_c, Qb_c);
        scan2_kernel<<<rows * 8, 256, 0, stream>>>(Pb_c, Qb_c);
        scan3_kernel<<<rows * 64, 256, 0, stream>>>(z_c, xs_c, proj_c,
                                                    Wdt + idx * 4096, bdt + idx * 256,
                                                    Alog + idx * 2048,
                                                    Dsk + idx * 256, Pb_c);
        gemm_wout<<<dim3(2, R / 128), 256, 0, stream>>>(
            xs_c, woutHs + (long long)idx * 65536, woutLs + (long long)idx * 65536,
            yC, dir, dir, dir ? ybk : nullptr);
        b0 += rows;
      }
    }
    combine_kernel<<<1, 64, 0, stream>>>(ybk, ys);
    ln_kernel<<<16384, 256, 0, stream>>>(hin, hs, yac, ys, lng + i * 256,
                                         lnb + i * 256, hbk);
    combine_kernel<<<1, 64, 0, stream>>>(hbk, sc + (i == 0 ? 9 : 11));
  }
  mean_part<<<2048, 256, 0, stream>>>(hbuf, sc + 11, mpart);
  mean_fin<<<32, 256, 0, stream>>>(mpart, pooled);
  fq_small<<<1, 256, 0, stream>>>(pooled, pooled, 8192);
  fq_small<<<1, 256, 0, stream>>>(clsw, clsq, 2560);
  cls_kernel<<<1, 320, 0, stream>>>(pooled, clsq, clsb, out);
}